// Round 9
// baseline (389.944 us; speedup 1.0000x reference)
//
#include <hip/hip_runtime.h>
#include <math.h>

#define NND 200000
#define NEV 100000
#define MD 100
#define TD 100
#define MSGD 172
#define NB 64
#define NFRAG 25          // 400 output cols (200 rz-combined | 100 i_n | 100 h_n)
#define KS 15             // K = 480
#define BP_ELEMS (KS * NFRAG * 64 * 8)
#define GLS 74            // Gl node stride (word-stride 37, coprime 32 -> conflict-free)
#define MROW 188          // msgbuf row stride in u32 (376 bf16 cols; col = dim + 4)

typedef __attribute__((ext_vector_type(8))) short bf16x8;
typedef __attribute__((ext_vector_type(4))) float f32x4;

__device__ __forceinline__ float sigmoidf_(float x) { return 1.0f / (1.0f + expf(-x)); }

__device__ __forceinline__ unsigned short f2bf(float f) {
    union { float f; unsigned int u; } v; v.f = f;
    unsigned int r = (v.u + 0x7FFFu + ((v.u >> 16) & 1u)) >> 16;
    return (unsigned short)r;
}
__device__ __forceinline__ float bf2f(unsigned int h) {
    union { unsigned int u; float f; } v; v.u = h << 16;
    return v.f;
}
__device__ __forceinline__ unsigned int pk(float a, float b) {
    return (unsigned int)f2bf(a) | ((unsigned int)f2bf(b) << 16);
}

// ---------------- K2: count events per node ----------------
__global__ __launch_bounds__(256) void k_count(
    const int* __restrict__ src, const int* __restrict__ dst, int* __restrict__ cnt)
{
    int e = blockIdx.x * 256 + threadIdx.x;
    if (e >= NEV) return;
    atomicAdd(&cnt[src[e]], 1);
    atomicAdd(&cnt[dst[e]], 1);
}

// ---------------- K3a: per-1024-block exclusive scan ----------------
__global__ __launch_bounds__(256) void k_scan1(
    const int* __restrict__ cnt, int* __restrict__ off, int* __restrict__ psum)
{
    __shared__ int sdat[256];
    int t = threadIdx.x, b = blockIdx.x;
    int i0 = b * 1024 + t * 4;
    int v0 = (i0 + 0 < NND) ? cnt[i0 + 0] : 0;
    int v1 = (i0 + 1 < NND) ? cnt[i0 + 1] : 0;
    int v2 = (i0 + 2 < NND) ? cnt[i0 + 2] : 0;
    int v3 = (i0 + 3 < NND) ? cnt[i0 + 3] : 0;
    int tsum = v0 + v1 + v2 + v3;
    sdat[t] = tsum;
    __syncthreads();
    for (int o = 1; o < 256; o <<= 1) {
        int x = (t >= o) ? sdat[t - o] : 0;
        __syncthreads();
        sdat[t] += x;
        __syncthreads();
    }
    int excl = sdat[t] - tsum;
    if (i0 + 0 < NND) off[i0 + 0] = excl;
    if (i0 + 1 < NND) off[i0 + 1] = excl + v0;
    if (i0 + 2 < NND) off[i0 + 2] = excl + v0 + v1;
    if (i0 + 3 < NND) off[i0 + 3] = excl + v0 + v1 + v2;
    if (t == 255) psum[b] = sdat[255];
}

// ---------------- K3b: scan block sums ----------------
__global__ __launch_bounds__(256) void k_scan2(int* __restrict__ psum, int nblk)
{
    __shared__ int sdat[256];
    int t = threadIdx.x;
    int v = (t < nblk) ? psum[t] : 0;
    sdat[t] = v;
    __syncthreads();
    for (int o = 1; o < 256; o <<= 1) {
        int x = (t >= o) ? sdat[t - o] : 0;
        __syncthreads();
        sdat[t] += x;
        __syncthreads();
    }
    if (t < nblk) psum[t] = sdat[t] - v;  // exclusive
}

// ---------------- K3c: add block offsets; init cursor ----------------
__global__ __launch_bounds__(256) void k_scan3(
    int* __restrict__ off, const int* __restrict__ psum, int* __restrict__ cur)
{
    int t = threadIdx.x, b = blockIdx.x;
    int base = psum[b];
    int i0 = b * 1024 + t * 4;
#pragma unroll
    for (int j = 0; j < 4; ++j) {
        int i = i0 + j;
        if (i < NND) {
            int v = off[i] + base;
            off[i] = v;
            cur[i] = v;
        }
    }
}

// ---------------- K4: place entries (other, eid, trel, node) ----------------
__global__ __launch_bounds__(256) void k_place(
    const int* __restrict__ src, const int* __restrict__ dst,
    const int* __restrict__ tarr, const int* __restrict__ last_update,
    int* __restrict__ cur, int4* __restrict__ entries)
{
    int e = blockIdx.x * 256 + threadIdx.x;
    if (e >= NEV) return;
    int s = src[e], d = dst[e], tt = tarr[e];
    int slot = atomicAdd(&cur[s], 1);
    entries[slot] = make_int4(d, e, __float_as_int((float)(tt - last_update[s])), s);
    slot = atomicAdd(&cur[d], 1);
    entries[slot] = make_int4(s, e, __float_as_int((float)(tt - last_update[d])), d);
}

// ---------------- weight prep: combined W~ in MFMA B-fragment order ----------------
__global__ __launch_bounds__(256) void tgn_prep(
    const float* __restrict__ w_ih, const float* __restrict__ w_hh,
    unsigned short* __restrict__ Bp)
{
    int idx = blockIdx.x * 256 + threadIdx.x;
    if (idx >= BP_ELEMS) return;
    int e = idx & 7;
    int lane = (idx >> 3) & 63;
    int t = idx >> 9;          // frag id = ks*25 + nf
    int nf = t % 25;
    int ks = t / 25;
    int col = nf * 16 + (lane & 15);
    int k = ks * 32 + ((lane >> 4) << 3) + e;
    float v = 0.0f;
    if (col < 200) {
        if (k < 472) v = w_ih[col * 472 + k];
        if (k < 100) v += w_hh[col * 100 + k];
    } else if (col < 300) {
        if (k < 472) v = w_ih[col * 472 + k];
    } else {
        if (k < 100) v = w_hh[(col - 100) * 100 + k];
    }
    Bp[idx] = f2bf(v);
}

// ---------------- K_memcvt: memory f32 -> bf16 padded rows [NND][104] ----------------
__global__ __launch_bounds__(256) void k_memcvt(
    const float* __restrict__ memory, uint4* __restrict__ membf)
{
    int idx = blockIdx.x * 256 + threadIdx.x;   // unit = node*13 + u
    if (idx >= NND * 13) return;
    int node = idx / 13, u = idx - node * 13;
    const float4* ms = reinterpret_cast<const float4*>(memory + (size_t)node * MD);
    uint4 o = (uint4){0u, 0u, 0u, 0u};
    if (u < 12) {
        float4 x = ms[2 * u], y = ms[2 * u + 1];
        o.x = pk(x.x, x.y); o.y = pk(x.z, x.w);
        o.z = pk(y.x, y.y); o.w = pk(y.z, y.w);
    } else {
        float4 x = ms[24];
        o.x = pk(x.x, x.y); o.y = pk(x.z, x.w);   // cols 100..103 stay zero
    }
    membf[idx] = o;
}

// ---------------- K_msg: materialize per-slot bf16 message rows ----------------
// msgbuf[slot][376 cols], col = dim+4: dims [0,100)=mem_other, [100,272)=raw_msg,
// [272,372)=cos-enc; cols 0..3 zero.  Stored as u32 pairs (lo=even col).
__global__ __launch_bounds__(256) void k_msg(
    const float* __restrict__ memory, const float* __restrict__ raw_msg,
    const float* __restrict__ time_w, const float* __restrict__ time_b,
    const int4* __restrict__ entries, unsigned int* __restrict__ msgbuf)
{
    int tid = threadIdx.x;
    int base = blockIdx.x * 8;   // 8 slots per block
    int sl[6], p[6];
    int4 en[6];
#pragma unroll
    for (int t = 0; t < 6; ++t) {
        int idx = t * 256 + tid;       // [0,1536)
        sl[t] = idx / 192;             // 0..7
        p[t] = idx - sl[t] * 192;      // 0..191 (active < 188)
        en[t] = entries[base + sl[t]];
    }
    float2 v[6];
#pragma unroll
    for (int t = 0; t < 6; ++t) {
        float2 r; r.x = 0.f; r.y = 0.f;
        int pp = p[t];
        if (pp >= 2 && pp < 188) {
            int j0 = 2 * pp - 4;
            if (j0 < 100) {
                r = *reinterpret_cast<const float2*>(memory + (size_t)en[t].x * MD + j0);
            } else if (j0 < 272) {
                r = *reinterpret_cast<const float2*>(raw_msg + (size_t)en[t].y * MSGD + (j0 - 100));
            } else {
                int t0 = j0 - 272;
                float trel = __int_as_float(en[t].z);
                float2 w = *reinterpret_cast<const float2*>(time_w + t0);
                float2 b = *reinterpret_cast<const float2*>(time_b + t0);
                r.x = cosf(trel * w.x + b.x);
                r.y = cosf(trel * w.y + b.y);
            }
        }
        v[t] = r;
    }
#pragma unroll
    for (int t = 0; t < 6; ++t) {
        if (p[t] < 188) {
            msgbuf[(size_t)(base + sl[t]) * MROW + p[t]] = pk(v[t].x, v[t].y);
        }
    }
}

// ---------------- K_gemm: fused reduce-stage + bf16 MFMA GRU ----------------
// Staging: wave handles 8 nodes; lane = 16B unit u of the 960B A-row.
// u<12: mem_self | u==12: mem 96..99 + msg dims 0..3 | 12<u<59: msg | u==59: pad.
// c<=1 rows are pure uint4 copies (membf / msgbuf); only c>=2 takes f32 accumulate.
__global__ __launch_bounds__(512, 4) void tgn_gemm(
    const float* __restrict__ memory, const uint4* __restrict__ membf,
    const unsigned int* __restrict__ msgbuf,
    const unsigned short* __restrict__ Bp,
    const float* __restrict__ b_ih, const float* __restrict__ b_hh,
    const int* __restrict__ cnt, const int* __restrict__ off,
    float* __restrict__ out)
{
    __shared__ __align__(16) unsigned short lds[64 * 480];  // A tile; reused as Gl[400][GLS]
    __shared__ int cnt_s[NB], off_s[NB];
    int tid = threadIdx.x;
    int n0 = blockIdx.x * NB;

    if (tid < NB) {
        cnt_s[tid] = cnt[n0 + tid];
        off_s[tid] = off[n0 + tid];
    }
    __syncthreads();

    int lane = tid & 63;
    int wv = tid >> 6;

    // ---- staging ----
    {
        const uint4* mb4 = reinterpret_cast<const uint4*>(msgbuf);
#pragma unroll 1
        for (int r = 0; r < 8; ++r) {
            int nl = wv * 8 + r;
            int c = cnt_s[nl];
            int o0 = off_s[nl];
            uint4 o = (uint4){0u, 0u, 0u, 0u};
            if (lane < 13)
                o = membf[(size_t)(n0 + nl) * 13 + lane];
            if (c == 1) {
                if (lane >= 12 && lane < 59) {
                    uint4 w = mb4[(size_t)o0 * 47 + (lane - 12)];
                    o.x |= w.x; o.y |= w.y; o.z |= w.z; o.w |= w.w;
                }
            } else if (c > 1) {
                if (lane >= 12 && lane < 59) {
                    int m = lane - 12;
                    float a0 = 0.f, a1 = 0.f, a2 = 0.f, a3 = 0.f;
                    float a4 = 0.f, a5 = 0.f, a6 = 0.f, a7 = 0.f;
                    for (int i = 0; i < c; ++i) {
                        uint4 w = mb4[(size_t)(o0 + i) * 47 + m];
                        a0 += bf2f(w.x & 0xffffu); a1 += bf2f(w.x >> 16);
                        a2 += bf2f(w.y & 0xffffu); a3 += bf2f(w.y >> 16);
                        a4 += bf2f(w.z & 0xffffu); a5 += bf2f(w.z >> 16);
                        a6 += bf2f(w.w & 0xffffu); a7 += bf2f(w.w >> 16);
                    }
                    float ci = 1.0f / (float)c;
                    unsigned int p2 = pk(a4 * ci, a5 * ci);
                    unsigned int p3 = pk(a6 * ci, a7 * ci);
                    if (lane > 12) {
                        o.x = pk(a0 * ci, a1 * ci);
                        o.y = pk(a2 * ci, a3 * ci);
                    }
                    o.z = p2; o.w = p3;
                }
            }
            if (lane < 60) {
                int byte = (nl * 960 + 16 * lane) ^ ((nl & 7) << 4);
                *reinterpret_cast<uint4*>(reinterpret_cast<char*>(lds) + byte) = o;
            }
        }
    }
    __syncthreads();

    // ---- MFMA phase ----
    int l15 = lane & 15;
    int kg8 = (lane >> 4) << 3;
    int f0 = (wv == 0) ? 0 : (4 + 3 * (wv - 1));
    int cw = (wv == 0) ? 4 : 3;

    f32x4 acc[4][4];
#pragma unroll
    for (int g = 0; g < 4; ++g)
#pragma unroll
        for (int i = 0; i < 4; ++i) acc[g][i] = (f32x4){0.f, 0.f, 0.f, 0.f};

    const bf16x8* BpB = reinterpret_cast<const bf16x8*>(Bp);
    const char* ldsc = reinterpret_cast<const char*>(lds);

    for (int ks = 0; ks < KS; ++ks) {
        int k0 = ks * 32 + kg8;
        const bf16x8* bp = BpB + ((size_t)(ks * NFRAG + f0)) * 64 + lane;
        bf16x8 b[4];
#pragma unroll
        for (int i = 0; i < 4; ++i)
            if (i < cw) b[i] = bp[i * 64];
#pragma unroll
        for (int g = 0; g < 4; ++g) {
            int r = g * 16 + l15;
            int ab = (r * 960 + 2 * k0) ^ ((r & 7) << 4);
            bf16x8 a = *reinterpret_cast<const bf16x8*>(ldsc + ab);
#pragma unroll
            for (int i = 0; i < 4; ++i)
                if (i < cw)
                    acc[g][i] = __builtin_amdgcn_mfma_f32_16x16x32_bf16(a, b[i], acc[g][i], 0, 0, 0);
        }
    }

    __syncthreads();  // reuse LDS as Gl[400][GLS] bf16

    unsigned short* Gl = lds;
    int kq = (lane >> 4) << 2;
#pragma unroll
    for (int i = 0; i < 4; ++i) {
        if (i < cw) {
            int col = (f0 + i) * 16 + l15;
            float bias = (col < 200) ? (b_ih[col] + b_hh[col])
                       : (col < 300) ? b_ih[col] : b_hh[col - 100];
#pragma unroll
            for (int g = 0; g < 4; ++g) {
                int node = g * 16 + kq;
#pragma unroll
                for (int rp = 0; rp < 2; ++rp) {
                    *reinterpret_cast<unsigned int*>(&Gl[col * GLS + node + 2 * rp]) =
                        pk(acc[g][i][2 * rp] + bias, acc[g][i][2 * rp + 1] + bias);
                }
            }
        }
    }
    __syncthreads();

    for (int idx = tid; idx < NB * MD; idx += 512) {
        int n = idx / MD, j = idx - n * MD;
        float rp = bf2f((unsigned int)Gl[j * GLS + n]);
        float zp = bf2f((unsigned int)Gl[(100 + j) * GLS + n]);
        float inp = bf2f((unsigned int)Gl[(200 + j) * GLS + n]);
        float hnp = bf2f((unsigned int)Gl[(300 + j) * GLS + n]);
        float r = sigmoidf_(rp);
        float z = sigmoidf_(zp);
        float nn = tanhf(inp + r * hnp);
        float mv = memory[(size_t)(n0 + n) * MD + j];
        float h = (1.0f - z) * nn + z * mv;
        out[(size_t)(n0 + n) * MD + j] = (cnt_s[n] > 0) ? h : mv;
    }
}

extern "C" void kernel_launch(void* const* d_in, const int* in_sizes, int n_in,
                              void* d_out, int out_size, void* d_ws, size_t ws_size,
                              hipStream_t stream)
{
    const float* memory      = (const float*)d_in[0];
    const float* raw_msg     = (const float*)d_in[1];
    const float* time_w      = (const float*)d_in[2];
    const float* time_b      = (const float*)d_in[3];
    const float* w_ih        = (const float*)d_in[4];
    const float* w_hh        = (const float*)d_in[5];
    const float* b_ih        = (const float*)d_in[6];
    const float* b_hh        = (const float*)d_in[7];
    const int*   last_update = (const int*)d_in[8];
    const int*   src         = (const int*)d_in[9];
    const int*   dst         = (const int*)d_in[10];
    const int*   tarr        = (const int*)d_in[11];
    float* out = (float*)d_out;

    // ws: cnt[N] off[N] cur[N] psum[256] | entries int4[2E] | msgbuf u32[2E*188]
    //     | membf uint4[N*13] | Bp
    int* cnt  = (int*)d_ws;
    int* off  = cnt + NND;
    int* cur  = off + NND;
    int* psum = cur + NND;
    int4* entries = (int4*)(psum + 256);
    unsigned int* msgbuf = (unsigned int*)(entries + 2 * NEV);
    uint4* membf = (uint4*)(msgbuf + (size_t)2 * NEV * MROW);
    unsigned short* Bp = (unsigned short*)(membf + (size_t)NND * 13);
    size_t need = (size_t)((char*)(Bp + BP_ELEMS) - (char*)d_ws);
    if (ws_size < need) return;

    const int NBLK = (NND + 1023) / 1024;  // 196
    const int NTILE = NND / NB;            // 3125

    hipMemsetAsync(cnt, 0, NND * sizeof(int), stream);
    tgn_prep<<<(BP_ELEMS + 255) / 256, 256, 0, stream>>>(w_ih, w_hh, Bp);
    k_memcvt<<<(NND * 13 + 255) / 256, 256, 0, stream>>>(memory, membf);
    k_count<<<(NEV + 255) / 256, 256, 0, stream>>>(src, dst, cnt);
    k_scan1<<<NBLK, 256, 0, stream>>>(cnt, off, psum);
    k_scan2<<<1, 256, 0, stream>>>(psum, NBLK);
    k_scan3<<<NBLK, 256, 0, stream>>>(off, psum, cur);
    k_place<<<(NEV + 255) / 256, 256, 0, stream>>>(src, dst, tarr, last_update, cur, entries);
    k_msg<<<2 * NEV / 8, 256, 0, stream>>>(memory, raw_msg, time_w, time_b, entries, msgbuf);
    tgn_gemm<<<NTILE, 512, 0, stream>>>(memory, membf, msgbuf, Bp, b_ih, b_hh, cnt, off, out);
}

// Round 10
// 343.888 us; speedup vs baseline: 1.1339x; 1.1339x over previous
//
#include <hip/hip_runtime.h>
#include <math.h>

#define NND 200000
#define NEV 100000
#define MD 100
#define TD 100
#define MSGD 172
#define NB 64
#define NFRAG 25          // 400 output cols (200 rz-combined | 100 i_n | 100 h_n)
#define KS 15             // K = 480
#define BP_ELEMS (KS * NFRAG * 64 * 8)
#define GLS 74            // Gl node stride (word-stride 37, coprime 32 -> conflict-free)
#define MROW 188          // msgbuf row stride in u32 (376 bf16 cols; col = dim + 4)

typedef __attribute__((ext_vector_type(8))) short bf16x8;
typedef __attribute__((ext_vector_type(4))) float f32x4;

__device__ __forceinline__ float sigmoidf_(float x) { return 1.0f / (1.0f + expf(-x)); }

__device__ __forceinline__ unsigned short f2bf(float f) {
    union { float f; unsigned int u; } v; v.f = f;
    unsigned int r = (v.u + 0x7FFFu + ((v.u >> 16) & 1u)) >> 16;
    return (unsigned short)r;
}
__device__ __forceinline__ float bf2f(unsigned int h) {
    union { unsigned int u; float f; } v; v.u = h << 16;
    return v.f;
}
__device__ __forceinline__ unsigned int pk(float a, float b) {
    return (unsigned int)f2bf(a) | ((unsigned int)f2bf(b) << 16);
}

// ---------------- K2: count events per node ----------------
__global__ __launch_bounds__(256) void k_count(
    const int* __restrict__ src, const int* __restrict__ dst, int* __restrict__ cnt)
{
    int e = blockIdx.x * 256 + threadIdx.x;
    if (e >= NEV) return;
    atomicAdd(&cnt[src[e]], 1);
    atomicAdd(&cnt[dst[e]], 1);
}

// ---------------- K3a: per-1024-block exclusive scan ----------------
__global__ __launch_bounds__(256) void k_scan1(
    const int* __restrict__ cnt, int* __restrict__ off, int* __restrict__ psum)
{
    __shared__ int sdat[256];
    int t = threadIdx.x, b = blockIdx.x;
    int i0 = b * 1024 + t * 4;
    int v0 = (i0 + 0 < NND) ? cnt[i0 + 0] : 0;
    int v1 = (i0 + 1 < NND) ? cnt[i0 + 1] : 0;
    int v2 = (i0 + 2 < NND) ? cnt[i0 + 2] : 0;
    int v3 = (i0 + 3 < NND) ? cnt[i0 + 3] : 0;
    int tsum = v0 + v1 + v2 + v3;
    sdat[t] = tsum;
    __syncthreads();
    for (int o = 1; o < 256; o <<= 1) {
        int x = (t >= o) ? sdat[t - o] : 0;
        __syncthreads();
        sdat[t] += x;
        __syncthreads();
    }
    int excl = sdat[t] - tsum;
    if (i0 + 0 < NND) off[i0 + 0] = excl;
    if (i0 + 1 < NND) off[i0 + 1] = excl + v0;
    if (i0 + 2 < NND) off[i0 + 2] = excl + v0 + v1;
    if (i0 + 3 < NND) off[i0 + 3] = excl + v0 + v1 + v2;
    if (t == 255) psum[b] = sdat[255];
}

// ---------------- K3b: scan block sums ----------------
__global__ __launch_bounds__(256) void k_scan2(int* __restrict__ psum, int nblk)
{
    __shared__ int sdat[256];
    int t = threadIdx.x;
    int v = (t < nblk) ? psum[t] : 0;
    sdat[t] = v;
    __syncthreads();
    for (int o = 1; o < 256; o <<= 1) {
        int x = (t >= o) ? sdat[t - o] : 0;
        __syncthreads();
        sdat[t] += x;
        __syncthreads();
    }
    if (t < nblk) psum[t] = sdat[t] - v;  // exclusive
}

// ---------------- K3c: add block offsets; init cursor ----------------
__global__ __launch_bounds__(256) void k_scan3(
    int* __restrict__ off, const int* __restrict__ psum, int* __restrict__ cur)
{
    int t = threadIdx.x, b = blockIdx.x;
    int base = psum[b];
    int i0 = b * 1024 + t * 4;
#pragma unroll
    for (int j = 0; j < 4; ++j) {
        int i = i0 + j;
        if (i < NND) {
            int v = off[i] + base;
            off[i] = v;
            cur[i] = v;
        }
    }
}

// ---------------- K4: place entries (other, eid, trel, node) ----------------
__global__ __launch_bounds__(256) void k_place(
    const int* __restrict__ src, const int* __restrict__ dst,
    const int* __restrict__ tarr, const int* __restrict__ last_update,
    int* __restrict__ cur, int4* __restrict__ entries)
{
    int e = blockIdx.x * 256 + threadIdx.x;
    if (e >= NEV) return;
    int s = src[e], d = dst[e], tt = tarr[e];
    int slot = atomicAdd(&cur[s], 1);
    entries[slot] = make_int4(d, e, __float_as_int((float)(tt - last_update[s])), s);
    slot = atomicAdd(&cur[d], 1);
    entries[slot] = make_int4(s, e, __float_as_int((float)(tt - last_update[d])), d);
}

// ---------------- weight prep: combined W~ in MFMA B-fragment order ----------------
__global__ __launch_bounds__(256) void tgn_prep(
    const float* __restrict__ w_ih, const float* __restrict__ w_hh,
    unsigned short* __restrict__ Bp)
{
    int idx = blockIdx.x * 256 + threadIdx.x;
    if (idx >= BP_ELEMS) return;
    int e = idx & 7;
    int lane = (idx >> 3) & 63;
    int t = idx >> 9;          // frag id = ks*25 + nf
    int nf = t % 25;
    int ks = t / 25;
    int col = nf * 16 + (lane & 15);
    int k = ks * 32 + ((lane >> 4) << 3) + e;
    float v = 0.0f;
    if (col < 200) {
        if (k < 472) v = w_ih[col * 472 + k];
        if (k < 100) v += w_hh[col * 100 + k];
    } else if (col < 300) {
        if (k < 472) v = w_ih[col * 472 + k];
    } else {
        if (k < 100) v = w_hh[(col - 100) * 100 + k];
    }
    Bp[idx] = f2bf(v);
}

// ---------------- K_memcvt: memory f32 -> bf16 padded rows [NND][104] ----------------
__global__ __launch_bounds__(256) void k_memcvt(
    const float* __restrict__ memory, uint4* __restrict__ membf)
{
    int idx = blockIdx.x * 256 + threadIdx.x;   // unit = node*13 + u
    if (idx >= NND * 13) return;
    int node = idx / 13, u = idx - node * 13;
    const float4* ms = reinterpret_cast<const float4*>(memory + (size_t)node * MD);
    uint4 o = (uint4){0u, 0u, 0u, 0u};
    if (u < 12) {
        float4 x = ms[2 * u], y = ms[2 * u + 1];
        o.x = pk(x.x, x.y); o.y = pk(x.z, x.w);
        o.z = pk(y.x, y.y); o.w = pk(y.z, y.w);
    } else {
        float4 x = ms[24];
        o.x = pk(x.x, x.y); o.y = pk(x.z, x.w);   // cols 100..103 stay zero
    }
    membf[idx] = o;
}

// ---------------- K_msg: materialize per-slot bf16 message rows ----------------
// msgbuf[slot][376 cols], col = dim+4: dims [0,100)=mem_other, [100,272)=raw_msg,
// [272,372)=cos-enc; cols 0..3 zero.  Stored as u32 pairs (lo=even col).
__global__ __launch_bounds__(256) void k_msg(
    const float* __restrict__ memory, const float* __restrict__ raw_msg,
    const float* __restrict__ time_w, const float* __restrict__ time_b,
    const int4* __restrict__ entries, unsigned int* __restrict__ msgbuf)
{
    int tid = threadIdx.x;
    int base = blockIdx.x * 8;   // 8 slots per block
    int sl[6], p[6];
    int4 en[6];
#pragma unroll
    for (int t = 0; t < 6; ++t) {
        int idx = t * 256 + tid;       // [0,1536)
        sl[t] = idx / 192;             // 0..7
        p[t] = idx - sl[t] * 192;      // 0..191 (active < 188)
        en[t] = entries[base + sl[t]];
    }
    float2 v[6];
#pragma unroll
    for (int t = 0; t < 6; ++t) {
        float2 r; r.x = 0.f; r.y = 0.f;
        int pp = p[t];
        if (pp >= 2 && pp < 188) {
            int j0 = 2 * pp - 4;
            if (j0 < 100) {
                r = *reinterpret_cast<const float2*>(memory + (size_t)en[t].x * MD + j0);
            } else if (j0 < 272) {
                r = *reinterpret_cast<const float2*>(raw_msg + (size_t)en[t].y * MSGD + (j0 - 100));
            } else {
                int t0 = j0 - 272;
                float trel = __int_as_float(en[t].z);
                float2 w = *reinterpret_cast<const float2*>(time_w + t0);
                float2 b = *reinterpret_cast<const float2*>(time_b + t0);
                r.x = cosf(trel * w.x + b.x);
                r.y = cosf(trel * w.y + b.y);
            }
        }
        v[t] = r;
    }
#pragma unroll
    for (int t = 0; t < 6; ++t) {
        if (p[t] < 188) {
            msgbuf[(size_t)(base + sl[t]) * MROW + p[t]] = pk(v[t].x, v[t].y);
        }
    }
}

// ---------------- K_gemm: fused reduce-stage + bf16 MFMA GRU ----------------
// Staging: wave handles 8 nodes; lane = 16B unit u of the 960B A-row.
// u<12: mem_self | u==12: mem 96..99 + msg dims 0..3 | 12<u<59: msg | u==59: pad.
// All 8 membf units + 8 first-event msg units batch-issued before any use.
__global__ __launch_bounds__(512, 4) void tgn_gemm(
    const float* __restrict__ memory, const uint4* __restrict__ membf,
    const unsigned int* __restrict__ msgbuf,
    const unsigned short* __restrict__ Bp,
    const float* __restrict__ b_ih, const float* __restrict__ b_hh,
    const int* __restrict__ cnt, const int* __restrict__ off,
    float* __restrict__ out)
{
    __shared__ __align__(16) unsigned short lds[64 * 480];  // A tile; reused as Gl[400][GLS]
    __shared__ int cnt_s[NB], off_s[NB];
    int tid = threadIdx.x;
    int n0 = blockIdx.x * NB;

    if (tid < NB) {
        cnt_s[tid] = cnt[n0 + tid];
        off_s[tid] = off[n0 + tid];
    }
    __syncthreads();

    int lane = tid & 63;
    int wv = tid >> 6;

    // ---- staging: batched independent loads, then combine ----
    {
        const uint4* mb4 = reinterpret_cast<const uint4*>(msgbuf);
        int nlb = wv * 8;
        bool mlane = (lane < 13);
        bool slane = (lane >= 12 && lane < 59);
        int m = lane - 12;
        int cc[8], oo[8];
        uint4 mreg[8], wreg[8];
#pragma unroll
        for (int r = 0; r < 8; ++r) { cc[r] = cnt_s[nlb + r]; oo[r] = off_s[nlb + r]; }
#pragma unroll
        for (int r = 0; r < 8; ++r)
            mreg[r] = mlane ? membf[(size_t)(n0 + nlb + r) * 13 + lane]
                            : (uint4){0u, 0u, 0u, 0u};
#pragma unroll
        for (int r = 0; r < 8; ++r)
            wreg[r] = (slane && cc[r] > 0) ? mb4[(size_t)oo[r] * 47 + m]
                                           : (uint4){0u, 0u, 0u, 0u};
#pragma unroll
        for (int r = 0; r < 8; ++r) {
            int c = cc[r];
            uint4 o = mreg[r];
            if (c == 1) {
                o.x |= wreg[r].x; o.y |= wreg[r].y; o.z |= wreg[r].z; o.w |= wreg[r].w;
            } else if (c > 1) {
                if (slane) {
                    float a0 = bf2f(wreg[r].x & 0xffffu), a1 = bf2f(wreg[r].x >> 16);
                    float a2 = bf2f(wreg[r].y & 0xffffu), a3 = bf2f(wreg[r].y >> 16);
                    float a4 = bf2f(wreg[r].z & 0xffffu), a5 = bf2f(wreg[r].z >> 16);
                    float a6 = bf2f(wreg[r].w & 0xffffu), a7 = bf2f(wreg[r].w >> 16);
                    for (int i = 1; i < c; ++i) {
                        uint4 w = mb4[(size_t)(oo[r] + i) * 47 + m];
                        a0 += bf2f(w.x & 0xffffu); a1 += bf2f(w.x >> 16);
                        a2 += bf2f(w.y & 0xffffu); a3 += bf2f(w.y >> 16);
                        a4 += bf2f(w.z & 0xffffu); a5 += bf2f(w.z >> 16);
                        a6 += bf2f(w.w & 0xffffu); a7 += bf2f(w.w >> 16);
                    }
                    float ci = 1.0f / (float)c;
                    if (lane > 12) {
                        o.x = pk(a0 * ci, a1 * ci);
                        o.y = pk(a2 * ci, a3 * ci);
                    }
                    o.z = pk(a4 * ci, a5 * ci);
                    o.w = pk(a6 * ci, a7 * ci);
                }
            }
            if (lane < 60) {
                int nl = nlb + r;
                int byte = (nl * 960 + 16 * lane) ^ ((nl & 7) << 4);
                *reinterpret_cast<uint4*>(reinterpret_cast<char*>(lds) + byte) = o;
            }
        }
    }
    __syncthreads();

    // ---- MFMA phase: fully unrolled K loop (compiler pipelines B loads) ----
    int l15 = lane & 15;
    int kg8 = (lane >> 4) << 3;
    int f0 = (wv == 0) ? 0 : (4 + 3 * (wv - 1));
    int cw = (wv == 0) ? 4 : 3;

    f32x4 acc[4][4];
#pragma unroll
    for (int g = 0; g < 4; ++g)
#pragma unroll
        for (int i = 0; i < 4; ++i) acc[g][i] = (f32x4){0.f, 0.f, 0.f, 0.f};

    const bf16x8* BpB = reinterpret_cast<const bf16x8*>(Bp);
    const char* ldsc = reinterpret_cast<const char*>(lds);

#pragma unroll
    for (int ks = 0; ks < KS; ++ks) {
        int k0 = ks * 32 + kg8;
        const bf16x8* bp = BpB + ((size_t)(ks * NFRAG + f0)) * 64 + lane;
        bf16x8 b[4];
#pragma unroll
        for (int i = 0; i < 4; ++i)
            if (i < cw) b[i] = bp[i * 64];
#pragma unroll
        for (int g = 0; g < 4; ++g) {
            int r = g * 16 + l15;
            int ab = (r * 960 + 2 * k0) ^ ((r & 7) << 4);
            bf16x8 a = *reinterpret_cast<const bf16x8*>(ldsc + ab);
#pragma unroll
            for (int i = 0; i < 4; ++i)
                if (i < cw)
                    acc[g][i] = __builtin_amdgcn_mfma_f32_16x16x32_bf16(a, b[i], acc[g][i], 0, 0, 0);
        }
    }

    // ---- epilogue mv prefetch: issue memory re-reads before the Gl barrier ----
    float mv[13];
#pragma unroll
    for (int t = 0; t < 13; ++t) {
        int idx = tid + t * 512;
        mv[t] = (idx < NB * MD) ? memory[(size_t)n0 * MD + idx] : 0.f;
    }

    __syncthreads();  // reuse LDS as Gl[400][GLS] bf16

    unsigned short* Gl = lds;
    int kq = (lane >> 4) << 2;
#pragma unroll
    for (int i = 0; i < 4; ++i) {
        if (i < cw) {
            int col = (f0 + i) * 16 + l15;
            float bias = (col < 200) ? (b_ih[col] + b_hh[col])
                       : (col < 300) ? b_ih[col] : b_hh[col - 100];
#pragma unroll
            for (int g = 0; g < 4; ++g) {
                int node = g * 16 + kq;
#pragma unroll
                for (int rp = 0; rp < 2; ++rp) {
                    *reinterpret_cast<unsigned int*>(&Gl[col * GLS + node + 2 * rp]) =
                        pk(acc[g][i][2 * rp] + bias, acc[g][i][2 * rp + 1] + bias);
                }
            }
        }
    }
    __syncthreads();

#pragma unroll
    for (int t = 0; t < 13; ++t) {
        int idx = tid + t * 512;
        if (idx < NB * MD) {
            int n = idx / MD, j = idx - n * MD;
            float rp = bf2f((unsigned int)Gl[j * GLS + n]);
            float zp = bf2f((unsigned int)Gl[(100 + j) * GLS + n]);
            float inp = bf2f((unsigned int)Gl[(200 + j) * GLS + n]);
            float hnp = bf2f((unsigned int)Gl[(300 + j) * GLS + n]);
            float r = sigmoidf_(rp);
            float z = sigmoidf_(zp);
            float nn = tanhf(inp + r * hnp);
            float h = (1.0f - z) * nn + z * mv[t];
            out[(size_t)n0 * MD + idx] = (cnt_s[n] > 0) ? h : mv[t];
        }
    }
}

extern "C" void kernel_launch(void* const* d_in, const int* in_sizes, int n_in,
                              void* d_out, int out_size, void* d_ws, size_t ws_size,
                              hipStream_t stream)
{
    const float* memory      = (const float*)d_in[0];
    const float* raw_msg     = (const float*)d_in[1];
    const float* time_w      = (const float*)d_in[2];
    const float* time_b      = (const float*)d_in[3];
    const float* w_ih        = (const float*)d_in[4];
    const float* w_hh        = (const float*)d_in[5];
    const float* b_ih        = (const float*)d_in[6];
    const float* b_hh        = (const float*)d_in[7];
    const int*   last_update = (const int*)d_in[8];
    const int*   src         = (const int*)d_in[9];
    const int*   dst         = (const int*)d_in[10];
    const int*   tarr        = (const int*)d_in[11];
    float* out = (float*)d_out;

    // ws: cnt[N] off[N] cur[N] psum[256] | entries int4[2E] | msgbuf u32[2E*188]
    //     | membf uint4[N*13] | Bp
    int* cnt  = (int*)d_ws;
    int* off  = cnt + NND;
    int* cur  = off + NND;
    int* psum = cur + NND;
    int4* entries = (int4*)(psum + 256);
    unsigned int* msgbuf = (unsigned int*)(entries + 2 * NEV);
    uint4* membf = (uint4*)(msgbuf + (size_t)2 * NEV * MROW);
    unsigned short* Bp = (unsigned short*)(membf + (size_t)NND * 13);
    size_t need = (size_t)((char*)(Bp + BP_ELEMS) - (char*)d_ws);
    if (ws_size < need) return;

    const int NBLK = (NND + 1023) / 1024;  // 196
    const int NTILE = NND / NB;            // 3125

    hipMemsetAsync(cnt, 0, NND * sizeof(int), stream);
    tgn_prep<<<(BP_ELEMS + 255) / 256, 256, 0, stream>>>(w_ih, w_hh, Bp);
    k_memcvt<<<(NND * 13 + 255) / 256, 256, 0, stream>>>(memory, membf);
    k_count<<<(NEV + 255) / 256, 256, 0, stream>>>(src, dst, cnt);
    k_scan1<<<NBLK, 256, 0, stream>>>(cnt, off, psum);
    k_scan2<<<1, 256, 0, stream>>>(psum, NBLK);
    k_scan3<<<NBLK, 256, 0, stream>>>(off, psum, cur);
    k_place<<<(NEV + 255) / 256, 256, 0, stream>>>(src, dst, tarr, last_update, cur, entries);
    k_msg<<<2 * NEV / 8, 256, 0, stream>>>(memory, raw_msg, time_w, time_b, entries, msgbuf);
    tgn_gemm<<<NTILE, 512, 0, stream>>>(memory, membf, msgbuf, Bp, b_ih, b_hh, cnt, off, out);
}

// Round 11
// 332.068 us; speedup vs baseline: 1.1743x; 1.0356x over previous
//
#include <hip/hip_runtime.h>
#include <math.h>

#define NND 200000
#define NEV 100000
#define MD 100
#define TD 100
#define MSGD 172
#define NB 64
#define NFRAG 25          // 400 output cols (200 rz-combined | 100 i_n | 100 h_n)
#define KS 15             // K = 480
#define BP_ELEMS (KS * NFRAG * 64 * 8)
#define GLS 74            // Gl node stride (word-stride 37, coprime 32 -> conflict-free)
#define MROW 188          // msgbuf row stride in u32 (376 bf16 cols; col = dim + 4)

typedef __attribute__((ext_vector_type(8))) short bf16x8;
typedef __attribute__((ext_vector_type(4))) float f32x4;

__device__ __forceinline__ float fast_sigmoid(float x) {
    return 1.0f / (1.0f + __expf(-x));
}
__device__ __forceinline__ float fast_tanh(float x) {
    // 2/(1+e^-2x) - 1; e^-2x -> inf for very negative x gives 2/inf-1 = -1 (safe)
    return fmaf(2.0f, 1.0f / (1.0f + __expf(-2.0f * x)), -1.0f);
}

__device__ __forceinline__ unsigned short f2bf(float f) {
    union { float f; unsigned int u; } v; v.f = f;
    unsigned int r = (v.u + 0x7FFFu + ((v.u >> 16) & 1u)) >> 16;
    return (unsigned short)r;
}
__device__ __forceinline__ float bf2f(unsigned int h) {
    union { unsigned int u; float f; } v; v.u = h << 16;
    return v.f;
}
__device__ __forceinline__ unsigned int pk(float a, float b) {
    unsigned int r;
    asm("v_cvt_pk_bf16_f32 %0, %1, %2" : "=v"(r) : "v"(a), "v"(b));
    return r;  // lo = bf16(a), hi = bf16(b), RNE
}

// ---------------- K2: count events per node ----------------
__global__ __launch_bounds__(256) void k_count(
    const int* __restrict__ src, const int* __restrict__ dst, int* __restrict__ cnt)
{
    int e = blockIdx.x * 256 + threadIdx.x;
    if (e >= NEV) return;
    atomicAdd(&cnt[src[e]], 1);
    atomicAdd(&cnt[dst[e]], 1);
}

// ---------------- K3a: per-1024-block exclusive scan ----------------
__global__ __launch_bounds__(256) void k_scan1(
    const int* __restrict__ cnt, int* __restrict__ off, int* __restrict__ psum)
{
    __shared__ int sdat[256];
    int t = threadIdx.x, b = blockIdx.x;
    int i0 = b * 1024 + t * 4;
    int v0 = (i0 + 0 < NND) ? cnt[i0 + 0] : 0;
    int v1 = (i0 + 1 < NND) ? cnt[i0 + 1] : 0;
    int v2 = (i0 + 2 < NND) ? cnt[i0 + 2] : 0;
    int v3 = (i0 + 3 < NND) ? cnt[i0 + 3] : 0;
    int tsum = v0 + v1 + v2 + v3;
    sdat[t] = tsum;
    __syncthreads();
    for (int o = 1; o < 256; o <<= 1) {
        int x = (t >= o) ? sdat[t - o] : 0;
        __syncthreads();
        sdat[t] += x;
        __syncthreads();
    }
    int excl = sdat[t] - tsum;
    if (i0 + 0 < NND) off[i0 + 0] = excl;
    if (i0 + 1 < NND) off[i0 + 1] = excl + v0;
    if (i0 + 2 < NND) off[i0 + 2] = excl + v0 + v1;
    if (i0 + 3 < NND) off[i0 + 3] = excl + v0 + v1 + v2;
    if (t == 255) psum[b] = sdat[255];
}

// ---------------- K3b: scan block sums ----------------
__global__ __launch_bounds__(256) void k_scan2(int* __restrict__ psum, int nblk)
{
    __shared__ int sdat[256];
    int t = threadIdx.x;
    int v = (t < nblk) ? psum[t] : 0;
    sdat[t] = v;
    __syncthreads();
    for (int o = 1; o < 256; o <<= 1) {
        int x = (t >= o) ? sdat[t - o] : 0;
        __syncthreads();
        sdat[t] += x;
        __syncthreads();
    }
    if (t < nblk) psum[t] = sdat[t] - v;  // exclusive
}

// ---------------- K3c: add block offsets; init cursor ----------------
__global__ __launch_bounds__(256) void k_scan3(
    int* __restrict__ off, const int* __restrict__ psum, int* __restrict__ cur)
{
    int t = threadIdx.x, b = blockIdx.x;
    int base = psum[b];
    int i0 = b * 1024 + t * 4;
#pragma unroll
    for (int j = 0; j < 4; ++j) {
        int i = i0 + j;
        if (i < NND) {
            int v = off[i] + base;
            off[i] = v;
            cur[i] = v;
        }
    }
}

// ---------------- K4: place entries (other, eid, trel, node) ----------------
__global__ __launch_bounds__(256) void k_place(
    const int* __restrict__ src, const int* __restrict__ dst,
    const int* __restrict__ tarr, const int* __restrict__ last_update,
    int* __restrict__ cur, int4* __restrict__ entries)
{
    int e = blockIdx.x * 256 + threadIdx.x;
    if (e >= NEV) return;
    int s = src[e], d = dst[e], tt = tarr[e];
    int slot = atomicAdd(&cur[s], 1);
    entries[slot] = make_int4(d, e, __float_as_int((float)(tt - last_update[s])), s);
    slot = atomicAdd(&cur[d], 1);
    entries[slot] = make_int4(s, e, __float_as_int((float)(tt - last_update[d])), d);
}

// ---------------- weight prep: combined W~ in MFMA B-fragment order ----------------
__global__ __launch_bounds__(256) void tgn_prep(
    const float* __restrict__ w_ih, const float* __restrict__ w_hh,
    unsigned short* __restrict__ Bp)
{
    int idx = blockIdx.x * 256 + threadIdx.x;
    if (idx >= BP_ELEMS) return;
    int e = idx & 7;
    int lane = (idx >> 3) & 63;
    int t = idx >> 9;          // frag id = ks*25 + nf
    int nf = t % 25;
    int ks = t / 25;
    int col = nf * 16 + (lane & 15);
    int k = ks * 32 + ((lane >> 4) << 3) + e;
    float v = 0.0f;
    if (col < 200) {
        if (k < 472) v = w_ih[col * 472 + k];
        if (k < 100) v += w_hh[col * 100 + k];
    } else if (col < 300) {
        if (k < 472) v = w_ih[col * 472 + k];
    } else {
        if (k < 100) v = w_hh[(col - 100) * 100 + k];
    }
    Bp[idx] = f2bf(v);
}

// ---------------- K_memcvt: memory f32 -> bf16 padded rows [NND][104] ----------------
__global__ __launch_bounds__(256) void k_memcvt(
    const float* __restrict__ memory, uint4* __restrict__ membf)
{
    int idx = blockIdx.x * 256 + threadIdx.x;   // unit = node*13 + u
    if (idx >= NND * 13) return;
    int node = idx / 13, u = idx - node * 13;
    const float4* ms = reinterpret_cast<const float4*>(memory + (size_t)node * MD);
    uint4 o = (uint4){0u, 0u, 0u, 0u};
    if (u < 12) {
        float4 x = ms[2 * u], y = ms[2 * u + 1];
        o.x = pk(x.x, x.y); o.y = pk(x.z, x.w);
        o.z = pk(y.x, y.y); o.w = pk(y.z, y.w);
    } else {
        float4 x = ms[24];
        o.x = pk(x.x, x.y); o.y = pk(x.z, x.w);   // cols 100..103 stay zero
    }
    membf[idx] = o;
}

// ---------------- K_msg: materialize per-slot bf16 message rows ----------------
// msgbuf[slot][376 cols], col = dim+4: dims [0,100)=mem_other, [100,272)=raw_msg,
// [272,372)=cos-enc; cols 0..3 zero.  Stored as u32 pairs (lo=even col).
__global__ __launch_bounds__(256) void k_msg(
    const float* __restrict__ memory, const float* __restrict__ raw_msg,
    const float* __restrict__ time_w, const float* __restrict__ time_b,
    const int4* __restrict__ entries, unsigned int* __restrict__ msgbuf)
{
    int tid = threadIdx.x;
    int base = blockIdx.x * 8;   // 8 slots per block
    int sl[6], p[6];
    int4 en[6];
#pragma unroll
    for (int t = 0; t < 6; ++t) {
        int idx = t * 256 + tid;       // [0,1536)
        sl[t] = idx / 192;             // 0..7
        p[t] = idx - sl[t] * 192;      // 0..191 (active < 188)
        en[t] = entries[base + sl[t]];
    }
    float2 v[6];
#pragma unroll
    for (int t = 0; t < 6; ++t) {
        float2 r; r.x = 0.f; r.y = 0.f;
        int pp = p[t];
        if (pp >= 2 && pp < 188) {
            int j0 = 2 * pp - 4;
            if (j0 < 100) {
                r = *reinterpret_cast<const float2*>(memory + (size_t)en[t].x * MD + j0);
            } else if (j0 < 272) {
                r = *reinterpret_cast<const float2*>(raw_msg + (size_t)en[t].y * MSGD + (j0 - 100));
            } else {
                int t0 = j0 - 272;
                float trel = __int_as_float(en[t].z);
                float2 w = *reinterpret_cast<const float2*>(time_w + t0);
                float2 b = *reinterpret_cast<const float2*>(time_b + t0);
                r.x = __cosf(fmaf(trel, w.x, b.x));
                r.y = __cosf(fmaf(trel, w.y, b.y));
            }
        }
        v[t] = r;
    }
#pragma unroll
    for (int t = 0; t < 6; ++t) {
        if (p[t] < 188) {
            msgbuf[(size_t)(base + sl[t]) * MROW + p[t]] = pk(v[t].x, v[t].y);
        }
    }
}

// ---------------- K_gemm: fused reduce-stage + bf16 MFMA GRU ----------------
// Staging: wave handles 8 nodes; lane = 16B unit u of the 960B A-row.
// u<12: mem_self | u==12: mem 96..99 + msg dims 0..3 | 12<u<59: msg | u==59: pad.
// All 8 membf units + 8 first-event msg units batch-issued before any use.
__global__ __launch_bounds__(512, 4) void tgn_gemm(
    const float* __restrict__ memory, const uint4* __restrict__ membf,
    const unsigned int* __restrict__ msgbuf,
    const unsigned short* __restrict__ Bp,
    const float* __restrict__ b_ih, const float* __restrict__ b_hh,
    const int* __restrict__ cnt, const int* __restrict__ off,
    float* __restrict__ out)
{
    __shared__ __align__(16) unsigned short lds[64 * 480];  // A tile; reused as Gl[400][GLS]
    __shared__ int cnt_s[NB], off_s[NB];
    int tid = threadIdx.x;
    int n0 = blockIdx.x * NB;

    if (tid < NB) {
        cnt_s[tid] = cnt[n0 + tid];
        off_s[tid] = off[n0 + tid];
    }
    __syncthreads();

    int lane = tid & 63;
    int wv = tid >> 6;

    // ---- staging: batched independent loads, then combine ----
    {
        const uint4* mb4 = reinterpret_cast<const uint4*>(msgbuf);
        int nlb = wv * 8;
        bool mlane = (lane < 13);
        bool slane = (lane >= 12 && lane < 59);
        int m = lane - 12;
        int cc[8], oo[8];
        uint4 mreg[8], wreg[8];
#pragma unroll
        for (int r = 0; r < 8; ++r) { cc[r] = cnt_s[nlb + r]; oo[r] = off_s[nlb + r]; }
#pragma unroll
        for (int r = 0; r < 8; ++r)
            mreg[r] = mlane ? membf[(size_t)(n0 + nlb + r) * 13 + lane]
                            : (uint4){0u, 0u, 0u, 0u};
#pragma unroll
        for (int r = 0; r < 8; ++r)
            wreg[r] = (slane && cc[r] > 0) ? mb4[(size_t)oo[r] * 47 + m]
                                           : (uint4){0u, 0u, 0u, 0u};
#pragma unroll
        for (int r = 0; r < 8; ++r) {
            int c = cc[r];
            uint4 o = mreg[r];
            if (c == 1) {
                o.x |= wreg[r].x; o.y |= wreg[r].y; o.z |= wreg[r].z; o.w |= wreg[r].w;
            } else if (c > 1) {
                if (slane) {
                    float a0 = bf2f(wreg[r].x & 0xffffu), a1 = bf2f(wreg[r].x >> 16);
                    float a2 = bf2f(wreg[r].y & 0xffffu), a3 = bf2f(wreg[r].y >> 16);
                    float a4 = bf2f(wreg[r].z & 0xffffu), a5 = bf2f(wreg[r].z >> 16);
                    float a6 = bf2f(wreg[r].w & 0xffffu), a7 = bf2f(wreg[r].w >> 16);
                    for (int i = 1; i < c; ++i) {
                        uint4 w = mb4[(size_t)(oo[r] + i) * 47 + m];
                        a0 += bf2f(w.x & 0xffffu); a1 += bf2f(w.x >> 16);
                        a2 += bf2f(w.y & 0xffffu); a3 += bf2f(w.y >> 16);
                        a4 += bf2f(w.z & 0xffffu); a5 += bf2f(w.z >> 16);
                        a6 += bf2f(w.w & 0xffffu); a7 += bf2f(w.w >> 16);
                    }
                    float ci = 1.0f / (float)c;
                    if (lane > 12) {
                        o.x = pk(a0 * ci, a1 * ci);
                        o.y = pk(a2 * ci, a3 * ci);
                    }
                    o.z = pk(a4 * ci, a5 * ci);
                    o.w = pk(a6 * ci, a7 * ci);
                }
            }
            if (lane < 60) {
                int nl = nlb + r;
                int byte = (nl * 960 + 16 * lane) ^ ((nl & 7) << 4);
                *reinterpret_cast<uint4*>(reinterpret_cast<char*>(lds) + byte) = o;
            }
        }
    }
    __syncthreads();

    // ---- MFMA phase: fully unrolled K loop (compiler pipelines B loads) ----
    int l15 = lane & 15;
    int kg8 = (lane >> 4) << 3;
    int f0 = (wv == 0) ? 0 : (4 + 3 * (wv - 1));
    int cw = (wv == 0) ? 4 : 3;

    f32x4 acc[4][4];
#pragma unroll
    for (int g = 0; g < 4; ++g)
#pragma unroll
        for (int i = 0; i < 4; ++i) acc[g][i] = (f32x4){0.f, 0.f, 0.f, 0.f};

    const bf16x8* BpB = reinterpret_cast<const bf16x8*>(Bp);
    const char* ldsc = reinterpret_cast<const char*>(lds);

#pragma unroll
    for (int ks = 0; ks < KS; ++ks) {
        int k0 = ks * 32 + kg8;
        const bf16x8* bp = BpB + ((size_t)(ks * NFRAG + f0)) * 64 + lane;
        bf16x8 b[4];
#pragma unroll
        for (int i = 0; i < 4; ++i)
            if (i < cw) b[i] = bp[i * 64];
#pragma unroll
        for (int g = 0; g < 4; ++g) {
            int r = g * 16 + l15;
            int ab = (r * 960 + 2 * k0) ^ ((r & 7) << 4);
            bf16x8 a = *reinterpret_cast<const bf16x8*>(ldsc + ab);
#pragma unroll
            for (int i = 0; i < 4; ++i)
                if (i < cw)
                    acc[g][i] = __builtin_amdgcn_mfma_f32_16x16x32_bf16(a, b[i], acc[g][i], 0, 0, 0);
        }
    }

    // ---- epilogue mv prefetch: issue memory re-reads before the Gl barrier ----
    float mv[13];
#pragma unroll
    for (int t = 0; t < 13; ++t) {
        int idx = tid + t * 512;
        mv[t] = (idx < NB * MD) ? memory[(size_t)n0 * MD + idx] : 0.f;
    }

    __syncthreads();  // reuse LDS as Gl[400][GLS] bf16

    unsigned short* Gl = lds;
    int kq = (lane >> 4) << 2;
#pragma unroll
    for (int i = 0; i < 4; ++i) {
        if (i < cw) {
            int col = (f0 + i) * 16 + l15;
            float bias = (col < 200) ? (b_ih[col] + b_hh[col])
                       : (col < 300) ? b_ih[col] : b_hh[col - 100];
#pragma unroll
            for (int g = 0; g < 4; ++g) {
                int node = g * 16 + kq;
#pragma unroll
                for (int rp = 0; rp < 2; ++rp) {
                    *reinterpret_cast<unsigned int*>(&Gl[col * GLS + node + 2 * rp]) =
                        pk(acc[g][i][2 * rp] + bias, acc[g][i][2 * rp + 1] + bias);
                }
            }
        }
    }
    __syncthreads();

#pragma unroll
    for (int t = 0; t < 13; ++t) {
        int idx = tid + t * 512;
        if (idx < NB * MD) {
            int n = idx / MD, j = idx - n * MD;
            float rp = bf2f((unsigned int)Gl[j * GLS + n]);
            float zp = bf2f((unsigned int)Gl[(100 + j) * GLS + n]);
            float inp = bf2f((unsigned int)Gl[(200 + j) * GLS + n]);
            float hnp = bf2f((unsigned int)Gl[(300 + j) * GLS + n]);
            float r = fast_sigmoid(rp);
            float z = fast_sigmoid(zp);
            float nn = fast_tanh(fmaf(r, hnp, inp));
            float h = (1.0f - z) * nn + z * mv[t];
            out[(size_t)n0 * MD + idx] = (cnt_s[n] > 0) ? h : mv[t];
        }
    }
}

extern "C" void kernel_launch(void* const* d_in, const int* in_sizes, int n_in,
                              void* d_out, int out_size, void* d_ws, size_t ws_size,
                              hipStream_t stream)
{
    const float* memory      = (const float*)d_in[0];
    const float* raw_msg     = (const float*)d_in[1];
    const float* time_w      = (const float*)d_in[2];
    const float* time_b      = (const float*)d_in[3];
    const float* w_ih        = (const float*)d_in[4];
    const float* w_hh        = (const float*)d_in[5];
    const float* b_ih        = (const float*)d_in[6];
    const float* b_hh        = (const float*)d_in[7];
    const int*   last_update = (const int*)d_in[8];
    const int*   src         = (const int*)d_in[9];
    const int*   dst         = (const int*)d_in[10];
    const int*   tarr        = (const int*)d_in[11];
    float* out = (float*)d_out;

    // ws: cnt[N] off[N] cur[N] psum[256] | entries int4[2E] | msgbuf u32[2E*188]
    //     | membf uint4[N*13] | Bp
    int* cnt  = (int*)d_ws;
    int* off  = cnt + NND;
    int* cur  = off + NND;
    int* psum = cur + NND;
    int4* entries = (int4*)(psum + 256);
    unsigned int* msgbuf = (unsigned int*)(entries + 2 * NEV);
    uint4* membf = (uint4*)(msgbuf + (size_t)2 * NEV * MROW);
    unsigned short* Bp = (unsigned short*)(membf + (size_t)NND * 13);
    size_t need = (size_t)((char*)(Bp + BP_ELEMS) - (char*)d_ws);
    if (ws_size < need) return;

    const int NBLK = (NND + 1023) / 1024;  // 196
    const int NTILE = NND / NB;            // 3125

    hipMemsetAsync(cnt, 0, NND * sizeof(int), stream);
    tgn_prep<<<(BP_ELEMS + 255) / 256, 256, 0, stream>>>(w_ih, w_hh, Bp);
    k_memcvt<<<(NND * 13 + 255) / 256, 256, 0, stream>>>(memory, membf);
    k_count<<<(NEV + 255) / 256, 256, 0, stream>>>(src, dst, cnt);
    k_scan1<<<NBLK, 256, 0, stream>>>(cnt, off, psum);
    k_scan2<<<1, 256, 0, stream>>>(psum, NBLK);
    k_scan3<<<NBLK, 256, 0, stream>>>(off, psum, cur);
    k_place<<<(NEV + 255) / 256, 256, 0, stream>>>(src, dst, tarr, last_update, cur, entries);
    k_msg<<<2 * NEV / 8, 256, 0, stream>>>(memory, raw_msg, time_w, time_b, entries, msgbuf);
    tgn_gemm<<<NTILE, 512, 0, stream>>>(memory, membf, msgbuf, Bp, b_ih, b_hh, cnt, off, out);
}

// Round 12
// 290.335 us; speedup vs baseline: 1.3431x; 1.1437x over previous
//
#include <hip/hip_runtime.h>
#include <math.h>

#define NND 200000
#define NEV 100000
#define MD 100
#define TD 100
#define MSGD 172
#define NB 64
#define NFRAG 25          // 400 output cols (200 rz-combined | 100 i_n | 100 h_n)
#define KS 15             // K = 480
#define BP_ELEMS (KS * NFRAG * 64 * 8)
#define GLS 74            // Gl node stride (word-stride 37, coprime 32 -> conflict-free)

typedef __attribute__((ext_vector_type(8))) short bf16x8;
typedef __attribute__((ext_vector_type(4))) float f32x4;

__device__ __forceinline__ float fast_sigmoid(float x) {
    return 1.0f / (1.0f + __expf(-x));
}
__device__ __forceinline__ float fast_tanh(float x) {
    return fmaf(2.0f, 1.0f / (1.0f + __expf(-2.0f * x)), -1.0f);
}

__device__ __forceinline__ unsigned short f2bf(float f) {
    union { float f; unsigned int u; } v; v.f = f;
    unsigned int r = (v.u + 0x7FFFu + ((v.u >> 16) & 1u)) >> 16;
    return (unsigned short)r;
}
__device__ __forceinline__ float bf2f(unsigned int h) {
    union { unsigned int u; float f; } v; v.u = h << 16;
    return v.f;
}
__device__ __forceinline__ unsigned int pk(float a, float b) {
    unsigned int r;
    asm("v_cvt_pk_bf16_f32 %0, %1, %2" : "=v"(r) : "v"(a), "v"(b));
    return r;  // lo = bf16(a), hi = bf16(b), RNE
}

// ---------------- K2: count events per node ----------------
__global__ __launch_bounds__(256) void k_count(
    const int* __restrict__ src, const int* __restrict__ dst, int* __restrict__ cnt)
{
    int e = blockIdx.x * 256 + threadIdx.x;
    if (e >= NEV) return;
    atomicAdd(&cnt[src[e]], 1);
    atomicAdd(&cnt[dst[e]], 1);
}

// ---------------- K3a: per-1024-block exclusive scan ----------------
__global__ __launch_bounds__(256) void k_scan1(
    const int* __restrict__ cnt, int* __restrict__ off, int* __restrict__ psum)
{
    __shared__ int sdat[256];
    int t = threadIdx.x, b = blockIdx.x;
    int i0 = b * 1024 + t * 4;
    int v0 = (i0 + 0 < NND) ? cnt[i0 + 0] : 0;
    int v1 = (i0 + 1 < NND) ? cnt[i0 + 1] : 0;
    int v2 = (i0 + 2 < NND) ? cnt[i0 + 2] : 0;
    int v3 = (i0 + 3 < NND) ? cnt[i0 + 3] : 0;
    int tsum = v0 + v1 + v2 + v3;
    sdat[t] = tsum;
    __syncthreads();
    for (int o = 1; o < 256; o <<= 1) {
        int x = (t >= o) ? sdat[t - o] : 0;
        __syncthreads();
        sdat[t] += x;
        __syncthreads();
    }
    int excl = sdat[t] - tsum;
    if (i0 + 0 < NND) off[i0 + 0] = excl;
    if (i0 + 1 < NND) off[i0 + 1] = excl + v0;
    if (i0 + 2 < NND) off[i0 + 2] = excl + v0 + v1;
    if (i0 + 3 < NND) off[i0 + 3] = excl + v0 + v1 + v2;
    if (t == 255) psum[b] = sdat[255];
}

// ---------------- K3b: scan block sums ----------------
__global__ __launch_bounds__(256) void k_scan2(int* __restrict__ psum, int nblk)
{
    __shared__ int sdat[256];
    int t = threadIdx.x;
    int v = (t < nblk) ? psum[t] : 0;
    sdat[t] = v;
    __syncthreads();
    for (int o = 1; o < 256; o <<= 1) {
        int x = (t >= o) ? sdat[t - o] : 0;
        __syncthreads();
        sdat[t] += x;
        __syncthreads();
    }
    if (t < nblk) psum[t] = sdat[t] - v;  // exclusive
}

// ---------------- K3c: add block offsets; init cursor ----------------
__global__ __launch_bounds__(256) void k_scan3(
    int* __restrict__ off, const int* __restrict__ psum, int* __restrict__ cur)
{
    int t = threadIdx.x, b = blockIdx.x;
    int base = psum[b];
    int i0 = b * 1024 + t * 4;
#pragma unroll
    for (int j = 0; j < 4; ++j) {
        int i = i0 + j;
        if (i < NND) {
            int v = off[i] + base;
            off[i] = v;
            cur[i] = v;
        }
    }
}

// ---------------- K4: place entries (other, eid, trel, node) ----------------
__global__ __launch_bounds__(256) void k_place(
    const int* __restrict__ src, const int* __restrict__ dst,
    const int* __restrict__ tarr, const int* __restrict__ last_update,
    int* __restrict__ cur, int4* __restrict__ entries)
{
    int e = blockIdx.x * 256 + threadIdx.x;
    if (e >= NEV) return;
    int s = src[e], d = dst[e], tt = tarr[e];
    int slot = atomicAdd(&cur[s], 1);
    entries[slot] = make_int4(d, e, __float_as_int((float)(tt - last_update[s])), s);
    slot = atomicAdd(&cur[d], 1);
    entries[slot] = make_int4(s, e, __float_as_int((float)(tt - last_update[d])), d);
}

// ---------------- weight prep: combined W~ in MFMA B-fragment order ----------------
__global__ __launch_bounds__(256) void tgn_prep(
    const float* __restrict__ w_ih, const float* __restrict__ w_hh,
    unsigned short* __restrict__ Bp)
{
    int idx = blockIdx.x * 256 + threadIdx.x;
    if (idx >= BP_ELEMS) return;
    int e = idx & 7;
    int lane = (idx >> 3) & 63;
    int t = idx >> 9;          // frag id = ks*25 + nf
    int nf = t % 25;
    int ks = t / 25;
    int col = nf * 16 + (lane & 15);
    int k = ks * 32 + ((lane >> 4) << 3) + e;
    float v = 0.0f;
    if (col < 200) {
        if (k < 472) v = w_ih[col * 472 + k];
        if (k < 100) v += w_hh[col * 100 + k];
    } else if (col < 300) {
        if (k < 472) v = w_ih[col * 472 + k];
    } else {
        if (k < 100) v = w_hh[(col - 100) * 100 + k];
    }
    Bp[idx] = f2bf(v);
}

// ---------------- K_memcvt: memory f32 -> bf16 padded rows [NND][104] ----------------
__global__ __launch_bounds__(256) void k_memcvt(
    const float* __restrict__ memory, uint4* __restrict__ membf)
{
    int idx = blockIdx.x * 256 + threadIdx.x;   // unit = node*13 + u
    if (idx >= NND * 13) return;
    int node = idx / 13, u = idx - node * 13;
    const float4* ms = reinterpret_cast<const float4*>(memory + (size_t)node * MD);
    uint4 o = (uint4){0u, 0u, 0u, 0u};
    if (u < 12) {
        float4 x = ms[2 * u], y = ms[2 * u + 1];
        o.x = pk(x.x, x.y); o.y = pk(x.z, x.w);
        o.z = pk(y.x, y.y); o.w = pk(y.z, y.w);
    } else {
        float4 x = ms[24];
        o.x = pk(x.x, x.y); o.y = pk(x.z, x.w);   // cols 100..103 stay zero
    }
    membf[idx] = o;
}

// ---------------- K_rawcvt: raw_msg f32 -> bf16 padded rows [NEV][176] ----------------
__global__ __launch_bounds__(256) void k_rawcvt(
    const float* __restrict__ raw_msg, uint4* __restrict__ rawbf)
{
    int idx = blockIdx.x * 256 + threadIdx.x;   // unit = eid*22 + r
    if (idx >= NEV * 22) return;
    int e = idx / 22, r = idx - e * 22;
    const float4* rs = reinterpret_cast<const float4*>(raw_msg + (size_t)e * MSGD);
    float4 x = rs[2 * r];
    float4 y = (float4){0.f, 0.f, 0.f, 0.f};
    if (2 * r + 1 < 43) y = rs[2 * r + 1];
    uint4 o;
    o.x = pk(x.x, x.y); o.y = pk(x.z, x.w);
    o.z = pk(y.x, y.y); o.w = pk(y.z, y.w);
    rawbf[idx] = o;
}

// ---------------- K_gemm: direct-gather stage + bf16 MFMA GRU ----------------
// A-row (480 cols): 0-99 self | 100-199 mean(mem_other) | 200-371 mean(raw) |
//                   372-471 mean(cos-enc) | 472-479 zero.
// Lane u stages 16B unit u: u<12 self(membf) | u==12 self hi + other 0-3 |
// 13<=u<=24 other (2x dwordx2 from membf[other], byte 16u-200) |
// 25<=u<=45 raw (rawbf[eid], byte 16u-400) | u==46 raw 168-171 + cos 0-3 |
// 47<=u<=58 cos (computed) | u==59 zero.
__global__ __launch_bounds__(512, 4) void tgn_gemm(
    const float* __restrict__ memory, const uint4* __restrict__ membf,
    const uint4* __restrict__ rawbf, const int4* __restrict__ entries,
    const float* __restrict__ time_w, const float* __restrict__ time_b,
    const unsigned short* __restrict__ Bp,
    const float* __restrict__ b_ih, const float* __restrict__ b_hh,
    const int* __restrict__ cnt, const int* __restrict__ off,
    float* __restrict__ out)
{
    __shared__ __align__(16) unsigned short lds[64 * 480];  // A tile; reused as Gl[400][GLS]
    __shared__ int cnt_s[NB], off_s[NB];
    int tid = threadIdx.x;
    int n0 = blockIdx.x * NB;

    if (tid < NB) {
        cnt_s[tid] = cnt[n0 + tid];
        off_s[tid] = off[n0 + tid];
    }
    __syncthreads();

    int lane = tid & 63;
    int wv = tid >> 6;

    // ---- staging ----
    {
        int u = lane;
        bool lOther = (u >= 13 && u <= 24);
        bool lRaw   = (u >= 25 && u <= 45);
        bool lMix   = (u == 12);
        bool lR46   = (u == 46);
        bool lTenc  = (u >= 47 && u <= 58);
        int offA = lOther ? (16 * u - 200) : (16 * u - 400);

        float tw[8], tb[8];
#pragma unroll
        for (int j = 0; j < 8; ++j) { tw[j] = 0.f; tb[j] = 0.f; }
        if (lTenc) {
            int d0 = 8 * u - 372;   // 4,12,...,92 -> 16B-aligned byte offsets
            float4 wa = *reinterpret_cast<const float4*>(time_w + d0);
            float4 wb = *reinterpret_cast<const float4*>(time_w + d0 + 4);
            float4 ba = *reinterpret_cast<const float4*>(time_b + d0);
            float4 bb = *reinterpret_cast<const float4*>(time_b + d0 + 4);
            tw[0] = wa.x; tw[1] = wa.y; tw[2] = wa.z; tw[3] = wa.w;
            tw[4] = wb.x; tw[5] = wb.y; tw[6] = wb.z; tw[7] = wb.w;
            tb[0] = ba.x; tb[1] = ba.y; tb[2] = ba.z; tb[3] = ba.w;
            tb[4] = bb.x; tb[5] = bb.y; tb[6] = bb.z; tb[7] = bb.w;
        } else if (lR46) {
            float4 wa = *reinterpret_cast<const float4*>(time_w);
            float4 ba = *reinterpret_cast<const float4*>(time_b);
            tw[4] = wa.x; tw[5] = wa.y; tw[6] = wa.z; tw[7] = wa.w;
            tb[4] = ba.x; tb[5] = ba.y; tb[6] = ba.z; tb[7] = ba.w;
        }

        const char* membc = reinterpret_cast<const char*>(membf);
        const char* rawbc = reinterpret_cast<const char*>(rawbf);

#pragma unroll
        for (int half = 0; half < 2; ++half) {
            int rb = wv * 8 + half * 4;   // local node base for this batch of 4
            int cc[4], oo[4];
#pragma unroll
            for (int r = 0; r < 4; ++r) { cc[r] = cnt_s[rb + r]; oo[r] = off_s[rb + r]; }
            int4 en[4];
#pragma unroll
            for (int r = 0; r < 4; ++r)
                en[r] = (cc[r] > 0) ? entries[oo[r]] : make_int4(0, 0, 0, 0);
            uint4 mreg[4];
#pragma unroll
            for (int r = 0; r < 4; ++r)
                mreg[r] = (u < 13) ? membf[(size_t)(n0 + rb + r) * 13 + u]
                                   : (uint4){0u, 0u, 0u, 0u};
            uint2 gA[4], gB[4];
#pragma unroll
            for (int r = 0; r < 4; ++r) {
                gA[r] = (uint2){0u, 0u}; gB[r] = (uint2){0u, 0u};
                if (cc[r] > 0) {
                    if (lOther) {
                        const char* p = membc + (size_t)en[r].x * 208 + offA;
                        gA[r] = *reinterpret_cast<const uint2*>(p);
                        gB[r] = *reinterpret_cast<const uint2*>(p + 8);
                    } else if (lMix) {
                        gB[r] = *reinterpret_cast<const uint2*>(membc + (size_t)en[r].x * 208);
                    } else if (lRaw) {
                        const char* p = rawbc + (size_t)en[r].y * 352 + offA;
                        gA[r] = *reinterpret_cast<const uint2*>(p);
                        gB[r] = *reinterpret_cast<const uint2*>(p + 8);
                    } else if (lR46) {
                        gA[r] = *reinterpret_cast<const uint2*>(rawbc + (size_t)en[r].y * 352 + 336);
                    }
                }
            }
#pragma unroll
            for (int r = 0; r < 4; ++r) {
                int c = cc[r];
                float a0 = bf2f(gA[r].x & 0xffffu), a1 = bf2f(gA[r].x >> 16);
                float a2 = bf2f(gA[r].y & 0xffffu), a3 = bf2f(gA[r].y >> 16);
                float a4 = bf2f(gB[r].x & 0xffffu), a5 = bf2f(gB[r].x >> 16);
                float a6 = bf2f(gB[r].y & 0xffffu), a7 = bf2f(gB[r].y >> 16);
                if ((lTenc || lR46) && c > 0) {
                    float trel = __int_as_float(en[r].z);
                    if (lTenc) {
                        a0 = __cosf(fmaf(trel, tw[0], tb[0]));
                        a1 = __cosf(fmaf(trel, tw[1], tb[1]));
                        a2 = __cosf(fmaf(trel, tw[2], tb[2]));
                        a3 = __cosf(fmaf(trel, tw[3], tb[3]));
                    }
                    a4 = __cosf(fmaf(trel, tw[4], tb[4]));
                    a5 = __cosf(fmaf(trel, tw[5], tb[5]));
                    a6 = __cosf(fmaf(trel, tw[6], tb[6]));
                    a7 = __cosf(fmaf(trel, tw[7], tb[7]));
                }
                for (int i = 1; i < c; ++i) {
                    int4 e2 = entries[oo[r] + i];
                    uint2 hA = (uint2){0u, 0u}, hB = (uint2){0u, 0u};
                    if (lOther) {
                        const char* p = membc + (size_t)e2.x * 208 + offA;
                        hA = *reinterpret_cast<const uint2*>(p);
                        hB = *reinterpret_cast<const uint2*>(p + 8);
                    } else if (lMix) {
                        hB = *reinterpret_cast<const uint2*>(membc + (size_t)e2.x * 208);
                    } else if (lRaw) {
                        const char* p = rawbc + (size_t)e2.y * 352 + offA;
                        hA = *reinterpret_cast<const uint2*>(p);
                        hB = *reinterpret_cast<const uint2*>(p + 8);
                    } else if (lR46) {
                        hA = *reinterpret_cast<const uint2*>(rawbc + (size_t)e2.y * 352 + 336);
                    }
                    a0 += bf2f(hA.x & 0xffffu); a1 += bf2f(hA.x >> 16);
                    a2 += bf2f(hA.y & 0xffffu); a3 += bf2f(hA.y >> 16);
                    a4 += bf2f(hB.x & 0xffffu); a5 += bf2f(hB.x >> 16);
                    a6 += bf2f(hB.y & 0xffffu); a7 += bf2f(hB.y >> 16);
                    if (lTenc || lR46) {
                        float trel = __int_as_float(e2.z);
                        if (lTenc) {
                            a0 += __cosf(fmaf(trel, tw[0], tb[0]));
                            a1 += __cosf(fmaf(trel, tw[1], tb[1]));
                            a2 += __cosf(fmaf(trel, tw[2], tb[2]));
                            a3 += __cosf(fmaf(trel, tw[3], tb[3]));
                        }
                        a4 += __cosf(fmaf(trel, tw[4], tb[4]));
                        a5 += __cosf(fmaf(trel, tw[5], tb[5]));
                        a6 += __cosf(fmaf(trel, tw[6], tb[6]));
                        a7 += __cosf(fmaf(trel, tw[7], tb[7]));
                    }
                }
                float ci = 1.0f / fmaxf((float)c, 1.0f);
                uint4 o;
                if (u < 12) {
                    o = mreg[r];
                } else if (u == 12) {
                    o.x = mreg[r].x; o.y = mreg[r].y;
                    o.z = pk(a4 * ci, a5 * ci); o.w = pk(a6 * ci, a7 * ci);
                } else {
                    o.x = pk(a0 * ci, a1 * ci); o.y = pk(a2 * ci, a3 * ci);
                    o.z = pk(a4 * ci, a5 * ci); o.w = pk(a6 * ci, a7 * ci);
                }
                if (u < 60) {
                    int nl = rb + r;
                    int byte = (nl * 960 + 16 * u) ^ ((nl & 7) << 4);
                    *reinterpret_cast<uint4*>(reinterpret_cast<char*>(lds) + byte) = o;
                }
            }
        }
    }
    __syncthreads();

    // ---- MFMA phase: fully unrolled K loop ----
    int l15 = lane & 15;
    int kg8 = (lane >> 4) << 3;
    int f0 = (wv == 0) ? 0 : (4 + 3 * (wv - 1));
    int cw = (wv == 0) ? 4 : 3;

    f32x4 acc[4][4];
#pragma unroll
    for (int g = 0; g < 4; ++g)
#pragma unroll
        for (int i = 0; i < 4; ++i) acc[g][i] = (f32x4){0.f, 0.f, 0.f, 0.f};

    const bf16x8* BpB = reinterpret_cast<const bf16x8*>(Bp);
    const char* ldsc = reinterpret_cast<const char*>(lds);

#pragma unroll
    for (int ks = 0; ks < KS; ++ks) {
        int k0 = ks * 32 + kg8;
        const bf16x8* bp = BpB + ((size_t)(ks * NFRAG + f0)) * 64 + lane;
        bf16x8 b[4];
#pragma unroll
        for (int i = 0; i < 4; ++i)
            if (i < cw) b[i] = bp[i * 64];
#pragma unroll
        for (int g = 0; g < 4; ++g) {
            int r = g * 16 + l15;
            int ab = (r * 960 + 2 * k0) ^ ((r & 7) << 4);
            bf16x8 a = *reinterpret_cast<const bf16x8*>(ldsc + ab);
#pragma unroll
            for (int i = 0; i < 4; ++i)
                if (i < cw)
                    acc[g][i] = __builtin_amdgcn_mfma_f32_16x16x32_bf16(a, b[i], acc[g][i], 0, 0, 0);
        }
    }

    // ---- epilogue mv prefetch ----
    float mv[13];
#pragma unroll
    for (int t = 0; t < 13; ++t) {
        int idx = tid + t * 512;
        mv[t] = (idx < NB * MD) ? memory[(size_t)n0 * MD + idx] : 0.f;
    }

    __syncthreads();  // reuse LDS as Gl[400][GLS] bf16

    unsigned short* Gl = lds;
    int kq = (lane >> 4) << 2;
#pragma unroll
    for (int i = 0; i < 4; ++i) {
        if (i < cw) {
            int col = (f0 + i) * 16 + l15;
            float bias = (col < 200) ? (b_ih[col] + b_hh[col])
                       : (col < 300) ? b_ih[col] : b_hh[col - 100];
#pragma unroll
            for (int g = 0; g < 4; ++g) {
                int node = g * 16 + kq;
#pragma unroll
                for (int rp = 0; rp < 2; ++rp) {
                    *reinterpret_cast<unsigned int*>(&Gl[col * GLS + node + 2 * rp]) =
                        pk(acc[g][i][2 * rp] + bias, acc[g][i][2 * rp + 1] + bias);
                }
            }
        }
    }
    __syncthreads();

#pragma unroll
    for (int t = 0; t < 13; ++t) {
        int idx = tid + t * 512;
        if (idx < NB * MD) {
            int n = idx / MD, j = idx - n * MD;
            float rp = bf2f((unsigned int)Gl[j * GLS + n]);
            float zp = bf2f((unsigned int)Gl[(100 + j) * GLS + n]);
            float inp = bf2f((unsigned int)Gl[(200 + j) * GLS + n]);
            float hnp = bf2f((unsigned int)Gl[(300 + j) * GLS + n]);
            float r = fast_sigmoid(rp);
            float z = fast_sigmoid(zp);
            float nn = fast_tanh(fmaf(r, hnp, inp));
            float h = (1.0f - z) * nn + z * mv[t];
            out[(size_t)n0 * MD + idx] = (cnt_s[n] > 0) ? h : mv[t];
        }
    }
}

extern "C" void kernel_launch(void* const* d_in, const int* in_sizes, int n_in,
                              void* d_out, int out_size, void* d_ws, size_t ws_size,
                              hipStream_t stream)
{
    const float* memory      = (const float*)d_in[0];
    const float* raw_msg     = (const float*)d_in[1];
    const float* time_w      = (const float*)d_in[2];
    const float* time_b      = (const float*)d_in[3];
    const float* w_ih        = (const float*)d_in[4];
    const float* w_hh        = (const float*)d_in[5];
    const float* b_ih        = (const float*)d_in[6];
    const float* b_hh        = (const float*)d_in[7];
    const int*   last_update = (const int*)d_in[8];
    const int*   src         = (const int*)d_in[9];
    const int*   dst         = (const int*)d_in[10];
    const int*   tarr        = (const int*)d_in[11];
    float* out = (float*)d_out;

    // ws: cnt[N] off[N] cur[N] psum[256] | entries int4[2E]
    //     | membf uint4[N*13] | rawbf uint4[E*22] | Bp
    int* cnt  = (int*)d_ws;
    int* off  = cnt + NND;
    int* cur  = off + NND;
    int* psum = cur + NND;
    int4* entries = (int4*)(psum + 256);
    uint4* membf = (uint4*)(entries + 2 * NEV);
    uint4* rawbf = membf + (size_t)NND * 13;
    unsigned short* Bp = (unsigned short*)(rawbf + (size_t)NEV * 22);
    size_t need = (size_t)((char*)(Bp + BP_ELEMS) - (char*)d_ws);
    if (ws_size < need) return;

    const int NBLK = (NND + 1023) / 1024;  // 196
    const int NTILE = NND / NB;            // 3125

    hipMemsetAsync(cnt, 0, NND * sizeof(int), stream);
    tgn_prep<<<(BP_ELEMS + 255) / 256, 256, 0, stream>>>(w_ih, w_hh, Bp);
    k_memcvt<<<(NND * 13 + 255) / 256, 256, 0, stream>>>(memory, membf);
    k_rawcvt<<<(NEV * 22 + 255) / 256, 256, 0, stream>>>(raw_msg, rawbf);
    k_count<<<(NEV + 255) / 256, 256, 0, stream>>>(src, dst, cnt);
    k_scan1<<<NBLK, 256, 0, stream>>>(cnt, off, psum);
    k_scan2<<<1, 256, 0, stream>>>(psum, NBLK);
    k_scan3<<<NBLK, 256, 0, stream>>>(off, psum, cur);
    k_place<<<(NEV + 255) / 256, 256, 0, stream>>>(src, dst, tarr, last_update, cur, entries);
    tgn_gemm<<<NTILE, 512, 0, stream>>>(memory, membf, rawbf, entries, time_w, time_b,
                                        Bp, b_ih, b_hh, cnt, off, out);
}

// Round 13
// 262.351 us; speedup vs baseline: 1.4863x; 1.1067x over previous
//
#include <hip/hip_runtime.h>
#include <math.h>

#define NND 200000
#define NEV 100000
#define MD 100
#define TD 100
#define MSGD 172
#define NB 64
#define NFRAG 25          // 400 output cols (200 rz-combined | 100 i_n | 100 h_n)
#define KS 15             // K = 480
#define BP_ELEMS (KS * NFRAG * 64 * 8)
#define GLS 74            // Gl node stride (word-stride 37, coprime 32 -> conflict-free)
#define ENT_CAP 256       // LDS entry cache capacity (mean per block = 64)

typedef __attribute__((ext_vector_type(8))) short bf16x8;
typedef __attribute__((ext_vector_type(4))) float f32x4;

__device__ __forceinline__ float fast_sigmoid(float x) {
    return 1.0f / (1.0f + __expf(-x));
}
__device__ __forceinline__ float fast_tanh(float x) {
    return fmaf(2.0f, 1.0f / (1.0f + __expf(-2.0f * x)), -1.0f);
}

__device__ __forceinline__ unsigned short f2bf(float f) {
    union { float f; unsigned int u; } v; v.f = f;
    unsigned int r = (v.u + 0x7FFFu + ((v.u >> 16) & 1u)) >> 16;
    return (unsigned short)r;
}
__device__ __forceinline__ float bf2f(unsigned int h) {
    union { unsigned int u; float f; } v; v.u = h << 16;
    return v.f;
}
__device__ __forceinline__ unsigned int pk(float a, float b) {
    unsigned int r;
    asm("v_cvt_pk_bf16_f32 %0, %1, %2" : "=v"(r) : "v"(a), "v"(b));
    return r;  // lo = bf16(a), hi = bf16(b), RNE
}

// ---------------- K2: count events per node ----------------
__global__ __launch_bounds__(256) void k_count(
    const int* __restrict__ src, const int* __restrict__ dst, int* __restrict__ cnt)
{
    int e = blockIdx.x * 256 + threadIdx.x;
    if (e >= NEV) return;
    atomicAdd(&cnt[src[e]], 1);
    atomicAdd(&cnt[dst[e]], 1);
}

// ---------------- K3a: per-1024-block exclusive scan ----------------
__global__ __launch_bounds__(256) void k_scan1(
    const int* __restrict__ cnt, int* __restrict__ off, int* __restrict__ psum)
{
    __shared__ int sdat[256];
    int t = threadIdx.x, b = blockIdx.x;
    int i0 = b * 1024 + t * 4;
    int v0 = (i0 + 0 < NND) ? cnt[i0 + 0] : 0;
    int v1 = (i0 + 1 < NND) ? cnt[i0 + 1] : 0;
    int v2 = (i0 + 2 < NND) ? cnt[i0 + 2] : 0;
    int v3 = (i0 + 3 < NND) ? cnt[i0 + 3] : 0;
    int tsum = v0 + v1 + v2 + v3;
    sdat[t] = tsum;
    __syncthreads();
    for (int o = 1; o < 256; o <<= 1) {
        int x = (t >= o) ? sdat[t - o] : 0;
        __syncthreads();
        sdat[t] += x;
        __syncthreads();
    }
    int excl = sdat[t] - tsum;
    if (i0 + 0 < NND) off[i0 + 0] = excl;
    if (i0 + 1 < NND) off[i0 + 1] = excl + v0;
    if (i0 + 2 < NND) off[i0 + 2] = excl + v0 + v1;
    if (i0 + 3 < NND) off[i0 + 3] = excl + v0 + v1 + v2;
    if (t == 255) psum[b] = sdat[255];
}

// ---------------- K3b: scan block sums ----------------
__global__ __launch_bounds__(256) void k_scan2(int* __restrict__ psum, int nblk)
{
    __shared__ int sdat[256];
    int t = threadIdx.x;
    int v = (t < nblk) ? psum[t] : 0;
    sdat[t] = v;
    __syncthreads();
    for (int o = 1; o < 256; o <<= 1) {
        int x = (t >= o) ? sdat[t - o] : 0;
        __syncthreads();
        sdat[t] += x;
        __syncthreads();
    }
    if (t < nblk) psum[t] = sdat[t] - v;  // exclusive
}

// ---------------- K3c: add block offsets; init cursor ----------------
__global__ __launch_bounds__(256) void k_scan3(
    int* __restrict__ off, const int* __restrict__ psum, int* __restrict__ cur)
{
    int t = threadIdx.x, b = blockIdx.x;
    int base = psum[b];
    int i0 = b * 1024 + t * 4;
#pragma unroll
    for (int j = 0; j < 4; ++j) {
        int i = i0 + j;
        if (i < NND) {
            int v = off[i] + base;
            off[i] = v;
            cur[i] = v;
        }
    }
}

// ---------------- K4: place entries (other, eid, trel, node) ----------------
__global__ __launch_bounds__(256) void k_place(
    const int* __restrict__ src, const int* __restrict__ dst,
    const int* __restrict__ tarr, const int* __restrict__ last_update,
    int* __restrict__ cur, int4* __restrict__ entries)
{
    int e = blockIdx.x * 256 + threadIdx.x;
    if (e >= NEV) return;
    int s = src[e], d = dst[e], tt = tarr[e];
    int slot = atomicAdd(&cur[s], 1);
    entries[slot] = make_int4(d, e, __float_as_int((float)(tt - last_update[s])), s);
    slot = atomicAdd(&cur[d], 1);
    entries[slot] = make_int4(s, e, __float_as_int((float)(tt - last_update[d])), d);
}

// ---------------- K_convert: fused weight-prep + memory->bf16 + raw->bf16 ----------------
// idx ranges: [0, BP_ELEMS) = Bp | next NND*13 = membf | next NEV*22 = rawbf
__global__ __launch_bounds__(256) void k_convert(
    const float* __restrict__ w_ih, const float* __restrict__ w_hh,
    const float* __restrict__ memory, const float* __restrict__ raw_msg,
    unsigned short* __restrict__ Bp, uint4* __restrict__ membf,
    uint4* __restrict__ rawbf)
{
    int idx = blockIdx.x * 256 + threadIdx.x;
    if (idx < BP_ELEMS) {
        int e = idx & 7;
        int lane = (idx >> 3) & 63;
        int t = idx >> 9;          // frag id = ks*25 + nf
        int nf = t % 25;
        int ks = t / 25;
        int col = nf * 16 + (lane & 15);
        int k = ks * 32 + ((lane >> 4) << 3) + e;
        float v = 0.0f;
        if (col < 200) {
            if (k < 472) v = w_ih[col * 472 + k];
            if (k < 100) v += w_hh[col * 100 + k];
        } else if (col < 300) {
            if (k < 472) v = w_ih[col * 472 + k];
        } else {
            if (k < 100) v = w_hh[(col - 100) * 100 + k];
        }
        Bp[idx] = f2bf(v);
        return;
    }
    int j = idx - BP_ELEMS;
    if (j < NND * 13) {
        int node = j / 13, u = j - node * 13;
        const float4* ms = reinterpret_cast<const float4*>(memory + (size_t)node * MD);
        uint4 o = (uint4){0u, 0u, 0u, 0u};
        if (u < 12) {
            float4 x = ms[2 * u], y = ms[2 * u + 1];
            o.x = pk(x.x, x.y); o.y = pk(x.z, x.w);
            o.z = pk(y.x, y.y); o.w = pk(y.z, y.w);
        } else {
            float4 x = ms[24];
            o.x = pk(x.x, x.y); o.y = pk(x.z, x.w);   // cols 100..103 stay zero
        }
        membf[j] = o;
        return;
    }
    j -= NND * 13;
    if (j < NEV * 22) {
        int e = j / 22, r = j - e * 22;
        const float4* rs = reinterpret_cast<const float4*>(raw_msg + (size_t)e * MSGD);
        float4 x = rs[2 * r];
        float4 y = (float4){0.f, 0.f, 0.f, 0.f};
        if (2 * r + 1 < 43) y = rs[2 * r + 1];
        uint4 o;
        o.x = pk(x.x, x.y); o.y = pk(x.z, x.w);
        o.z = pk(y.x, y.y); o.w = pk(y.z, y.w);
        rawbf[j] = o;
    }
}

// ---------------- K_gemm: direct-gather stage + bf16 MFMA GRU ----------------
// A-row (480 cols): 0-99 self | 100-199 mean(mem_other) | 200-371 mean(raw) |
//                   372-471 mean(cos-enc) | 472-479 zero.
// Lane u stages 16B unit u: u<12 self(membf) | u==12 self hi + other 0-3 |
// 13<=u<=24 other (membf[other], byte 16u-200) | 25<=u<=45 raw (rawbf[eid], 16u-400) |
// u==46 raw 168-171 + cos 0-3 | 47<=u<=58 cos (computed) | u==59 zero.
// Block entry range [off[n0], off[n0+64)) is prefetched into LDS (ENT_CAP cap).
__global__ __launch_bounds__(512, 4) void tgn_gemm(
    const uint4* __restrict__ membf,
    const uint4* __restrict__ rawbf, const int4* __restrict__ entries,
    const float* __restrict__ time_w, const float* __restrict__ time_b,
    const unsigned short* __restrict__ Bp,
    const float* __restrict__ b_ih, const float* __restrict__ b_hh,
    const int* __restrict__ cnt, const int* __restrict__ off,
    float* __restrict__ out)
{
    __shared__ __align__(16) unsigned short lds[64 * 480];  // A tile; reused as Gl[400][GLS]
    __shared__ int cnt_s[NB], off_s[NB];
    __shared__ __align__(16) int4 ent_s[ENT_CAP];
    int tid = threadIdx.x;
    int n0 = blockIdx.x * NB;

    int s0 = off[n0];
    int s1 = (n0 + NB < NND) ? off[n0 + NB] : (2 * NEV);
    int m = s1 - s0;
    bool lds_ok = (m <= ENT_CAP);
    if (tid < NB) {
        cnt_s[tid] = cnt[n0 + tid];
        off_s[tid] = off[n0 + tid];
    }
    if (lds_ok) {
        for (int i = tid; i < m; i += 512) ent_s[i] = entries[s0 + i];
    }
    __syncthreads();

    int lane = tid & 63;
    int wv = tid >> 6;

    auto getent = [&](int slot) -> int4 {
        return lds_ok ? ent_s[slot - s0] : entries[slot];
    };

    // ---- staging ----
    {
        int u = lane;
        bool lOther = (u >= 13 && u <= 24);
        bool lRaw   = (u >= 25 && u <= 45);
        bool lMix   = (u == 12);
        bool lR46   = (u == 46);
        bool lTenc  = (u >= 47 && u <= 58);
        int offA = lOther ? (16 * u - 200) : (16 * u - 400);

        float tw[8], tb[8];
#pragma unroll
        for (int j = 0; j < 8; ++j) { tw[j] = 0.f; tb[j] = 0.f; }
        if (lTenc) {
            int d0 = 8 * u - 372;
            float4 wa = *reinterpret_cast<const float4*>(time_w + d0);
            float4 wb = *reinterpret_cast<const float4*>(time_w + d0 + 4);
            float4 ba = *reinterpret_cast<const float4*>(time_b + d0);
            float4 bb = *reinterpret_cast<const float4*>(time_b + d0 + 4);
            tw[0] = wa.x; tw[1] = wa.y; tw[2] = wa.z; tw[3] = wa.w;
            tw[4] = wb.x; tw[5] = wb.y; tw[6] = wb.z; tw[7] = wb.w;
            tb[0] = ba.x; tb[1] = ba.y; tb[2] = ba.z; tb[3] = ba.w;
            tb[4] = bb.x; tb[5] = bb.y; tb[6] = bb.z; tb[7] = bb.w;
        } else if (lR46) {
            float4 wa = *reinterpret_cast<const float4*>(time_w);
            float4 ba = *reinterpret_cast<const float4*>(time_b);
            tw[4] = wa.x; tw[5] = wa.y; tw[6] = wa.z; tw[7] = wa.w;
            tb[4] = ba.x; tb[5] = ba.y; tb[6] = ba.z; tb[7] = ba.w;
        }

        const char* membc = reinterpret_cast<const char*>(membf);
        const char* rawbc = reinterpret_cast<const char*>(rawbf);

#pragma unroll
        for (int half = 0; half < 2; ++half) {
            int rb = wv * 8 + half * 4;   // local node base for this batch of 4
            int cc[4], oo[4];
#pragma unroll
            for (int r = 0; r < 4; ++r) { cc[r] = cnt_s[rb + r]; oo[r] = off_s[rb + r]; }
            int4 en[4];
#pragma unroll
            for (int r = 0; r < 4; ++r)
                en[r] = (cc[r] > 0) ? getent(oo[r]) : make_int4(0, 0, 0, 0);
            uint4 mreg[4];
#pragma unroll
            for (int r = 0; r < 4; ++r)
                mreg[r] = (u < 13) ? membf[(size_t)(n0 + rb + r) * 13 + u]
                                   : (uint4){0u, 0u, 0u, 0u};
            uint2 gA[4], gB[4];
#pragma unroll
            for (int r = 0; r < 4; ++r) {
                gA[r] = (uint2){0u, 0u}; gB[r] = (uint2){0u, 0u};
                if (cc[r] > 0) {
                    if (lOther) {
                        const char* p = membc + (size_t)en[r].x * 208 + offA;
                        gA[r] = *reinterpret_cast<const uint2*>(p);
                        gB[r] = *reinterpret_cast<const uint2*>(p + 8);
                    } else if (lMix) {
                        gB[r] = *reinterpret_cast<const uint2*>(membc + (size_t)en[r].x * 208);
                    } else if (lRaw) {
                        const char* p = rawbc + (size_t)en[r].y * 352 + offA;
                        gA[r] = *reinterpret_cast<const uint2*>(p);
                        gB[r] = *reinterpret_cast<const uint2*>(p + 8);
                    } else if (lR46) {
                        gA[r] = *reinterpret_cast<const uint2*>(rawbc + (size_t)en[r].y * 352 + 336);
                    }
                }
            }
#pragma unroll
            for (int r = 0; r < 4; ++r) {
                int c = cc[r];
                float a0 = bf2f(gA[r].x & 0xffffu), a1 = bf2f(gA[r].x >> 16);
                float a2 = bf2f(gA[r].y & 0xffffu), a3 = bf2f(gA[r].y >> 16);
                float a4 = bf2f(gB[r].x & 0xffffu), a5 = bf2f(gB[r].x >> 16);
                float a6 = bf2f(gB[r].y & 0xffffu), a7 = bf2f(gB[r].y >> 16);
                if ((lTenc || lR46) && c > 0) {
                    float trel = __int_as_float(en[r].z);
                    if (lTenc) {
                        a0 = __cosf(fmaf(trel, tw[0], tb[0]));
                        a1 = __cosf(fmaf(trel, tw[1], tb[1]));
                        a2 = __cosf(fmaf(trel, tw[2], tb[2]));
                        a3 = __cosf(fmaf(trel, tw[3], tb[3]));
                    }
                    a4 = __cosf(fmaf(trel, tw[4], tb[4]));
                    a5 = __cosf(fmaf(trel, tw[5], tb[5]));
                    a6 = __cosf(fmaf(trel, tw[6], tb[6]));
                    a7 = __cosf(fmaf(trel, tw[7], tb[7]));
                }
                int4 e2 = (c > 1) ? getent(oo[r] + 1) : en[r];
                for (int i = 1; i < c; ++i) {
                    int4 ecur = e2;
                    if (i + 1 < c) e2 = getent(oo[r] + i + 1);  // prefetch next entry
                    uint2 hA = (uint2){0u, 0u}, hB = (uint2){0u, 0u};
                    if (lOther) {
                        const char* p = membc + (size_t)ecur.x * 208 + offA;
                        hA = *reinterpret_cast<const uint2*>(p);
                        hB = *reinterpret_cast<const uint2*>(p + 8);
                    } else if (lMix) {
                        hB = *reinterpret_cast<const uint2*>(membc + (size_t)ecur.x * 208);
                    } else if (lRaw) {
                        const char* p = rawbc + (size_t)ecur.y * 352 + offA;
                        hA = *reinterpret_cast<const uint2*>(p);
                        hB = *reinterpret_cast<const uint2*>(p + 8);
                    } else if (lR46) {
                        hA = *reinterpret_cast<const uint2*>(rawbc + (size_t)ecur.y * 352 + 336);
                    }
                    a0 += bf2f(hA.x & 0xffffu); a1 += bf2f(hA.x >> 16);
                    a2 += bf2f(hA.y & 0xffffu); a3 += bf2f(hA.y >> 16);
                    a4 += bf2f(hB.x & 0xffffu); a5 += bf2f(hB.x >> 16);
                    a6 += bf2f(hB.y & 0xffffu); a7 += bf2f(hB.y >> 16);
                    if (lTenc || lR46) {
                        float trel = __int_as_float(ecur.z);
                        if (lTenc) {
                            a0 += __cosf(fmaf(trel, tw[0], tb[0]));
                            a1 += __cosf(fmaf(trel, tw[1], tb[1]));
                            a2 += __cosf(fmaf(trel, tw[2], tb[2]));
                            a3 += __cosf(fmaf(trel, tw[3], tb[3]));
                        }
                        a4 += __cosf(fmaf(trel, tw[4], tb[4]));
                        a5 += __cosf(fmaf(trel, tw[5], tb[5]));
                        a6 += __cosf(fmaf(trel, tw[6], tb[6]));
                        a7 += __cosf(fmaf(trel, tw[7], tb[7]));
                    }
                }
                float ci = 1.0f / fmaxf((float)c, 1.0f);
                uint4 o;
                if (u < 12) {
                    o = mreg[r];
                } else if (u == 12) {
                    o.x = mreg[r].x; o.y = mreg[r].y;
                    o.z = pk(a4 * ci, a5 * ci); o.w = pk(a6 * ci, a7 * ci);
                } else {
                    o.x = pk(a0 * ci, a1 * ci); o.y = pk(a2 * ci, a3 * ci);
                    o.z = pk(a4 * ci, a5 * ci); o.w = pk(a6 * ci, a7 * ci);
                }
                if (u < 60) {
                    int nl = rb + r;
                    int byte = (nl * 960 + 16 * u) ^ ((nl & 7) << 4);
                    *reinterpret_cast<uint4*>(reinterpret_cast<char*>(lds) + byte) = o;
                }
            }
        }
    }
    __syncthreads();

    // ---- MFMA phase: fully unrolled K loop ----
    int l15 = lane & 15;
    int kg8 = (lane >> 4) << 3;
    int f0 = (wv == 0) ? 0 : (4 + 3 * (wv - 1));
    int cw = (wv == 0) ? 4 : 3;

    f32x4 acc[4][4];
#pragma unroll
    for (int g = 0; g < 4; ++g)
#pragma unroll
        for (int i = 0; i < 4; ++i) acc[g][i] = (f32x4){0.f, 0.f, 0.f, 0.f};

    const bf16x8* BpB = reinterpret_cast<const bf16x8*>(Bp);
    const char* ldsc = reinterpret_cast<const char*>(lds);

#pragma unroll
    for (int ks = 0; ks < KS; ++ks) {
        int k0 = ks * 32 + kg8;
        const bf16x8* bp = BpB + ((size_t)(ks * NFRAG + f0)) * 64 + lane;
        bf16x8 b[4];
#pragma unroll
        for (int i = 0; i < 4; ++i)
            if (i < cw) b[i] = bp[i * 64];
#pragma unroll
        for (int g = 0; g < 4; ++g) {
            int r = g * 16 + l15;
            int ab = (r * 960 + 2 * k0) ^ ((r & 7) << 4);
            bf16x8 a = *reinterpret_cast<const bf16x8*>(ldsc + ab);
#pragma unroll
            for (int i = 0; i < 4; ++i)
                if (i < cw)
                    acc[g][i] = __builtin_amdgcn_mfma_f32_16x16x32_bf16(a, b[i], acc[g][i], 0, 0, 0);
        }
    }

    // ---- epilogue mv prefetch (from bf16 membf; col j<100 is byte node*208+2j) ----
    float mv[13];
    {
        const char* membc = reinterpret_cast<const char*>(membf);
#pragma unroll
        for (int t = 0; t < 13; ++t) {
            int idx = tid + t * 512;
            if (idx < NB * MD) {
                int n = idx / MD, j = idx - n * MD;
                unsigned short h = *reinterpret_cast<const unsigned short*>(
                    membc + (size_t)(n0 + n) * 208 + 2 * j);
                mv[t] = bf2f((unsigned int)h);
            } else {
                mv[t] = 0.f;
            }
        }
    }

    __syncthreads();  // reuse LDS as Gl[400][GLS] bf16

    unsigned short* Gl = lds;
    int kq = (lane >> 4) << 2;
#pragma unroll
    for (int i = 0; i < 4; ++i) {
        if (i < cw) {
            int col = (f0 + i) * 16 + l15;
            float bias = (col < 200) ? (b_ih[col] + b_hh[col])
                       : (col < 300) ? b_ih[col] : b_hh[col - 100];
#pragma unroll
            for (int g = 0; g < 4; ++g) {
                int node = g * 16 + kq;
#pragma unroll
                for (int rp = 0; rp < 2; ++rp) {
                    *reinterpret_cast<unsigned int*>(&Gl[col * GLS + node + 2 * rp]) =
                        pk(acc[g][i][2 * rp] + bias, acc[g][i][2 * rp + 1] + bias);
                }
            }
        }
    }
    __syncthreads();

#pragma unroll
    for (int t = 0; t < 13; ++t) {
        int idx = tid + t * 512;
        if (idx < NB * MD) {
            int n = idx / MD, j = idx - n * MD;
            float rp = bf2f((unsigned int)Gl[j * GLS + n]);
            float zp = bf2f((unsigned int)Gl[(100 + j) * GLS + n]);
            float inp = bf2f((unsigned int)Gl[(200 + j) * GLS + n]);
            float hnp = bf2f((unsigned int)Gl[(300 + j) * GLS + n]);
            float r = fast_sigmoid(rp);
            float z = fast_sigmoid(zp);
            float nn = fast_tanh(fmaf(r, hnp, inp));
            float h = (1.0f - z) * nn + z * mv[t];
            out[(size_t)n0 * MD + idx] = (cnt_s[n] > 0) ? h : mv[t];
        }
    }
}

extern "C" void kernel_launch(void* const* d_in, const int* in_sizes, int n_in,
                              void* d_out, int out_size, void* d_ws, size_t ws_size,
                              hipStream_t stream)
{
    const float* memory      = (const float*)d_in[0];
    const float* raw_msg     = (const float*)d_in[1];
    const float* time_w      = (const float*)d_in[2];
    const float* time_b      = (const float*)d_in[3];
    const float* w_ih        = (const float*)d_in[4];
    const float* w_hh        = (const float*)d_in[5];
    const float* b_ih        = (const float*)d_in[6];
    const float* b_hh        = (const float*)d_in[7];
    const int*   last_update = (const int*)d_in[8];
    const int*   src         = (const int*)d_in[9];
    const int*   dst         = (const int*)d_in[10];
    const int*   tarr        = (const int*)d_in[11];
    float* out = (float*)d_out;

    // ws: cnt[N] off[N] cur[N] psum[256] | entries int4[2E]
    //     | membf uint4[N*13] | rawbf uint4[E*22] | Bp
    int* cnt  = (int*)d_ws;
    int* off  = cnt + NND;
    int* cur  = off + NND;
    int* psum = cur + NND;
    int4* entries = (int4*)(psum + 256);
    uint4* membf = (uint4*)(entries + 2 * NEV);
    uint4* rawbf = membf + (size_t)NND * 13;
    unsigned short* Bp = (unsigned short*)(rawbf + (size_t)NEV * 22);
    size_t need = (size_t)((char*)(Bp + BP_ELEMS) - (char*)d_ws);
    if (ws_size < need) return;

    const int NBLK = (NND + 1023) / 1024;  // 196
    const int NTILE = NND / NB;            // 3125
    const int CVT_TOTAL = BP_ELEMS + NND * 13 + NEV * 22;

    hipMemsetAsync(cnt, 0, NND * sizeof(int), stream);
    k_convert<<<(CVT_TOTAL + 255) / 256, 256, 0, stream>>>(w_ih, w_hh, memory, raw_msg,
                                                           Bp, membf, rawbf);
    k_count<<<(NEV + 255) / 256, 256, 0, stream>>>(src, dst, cnt);
    k_scan1<<<NBLK, 256, 0, stream>>>(cnt, off, psum);
    k_scan2<<<1, 256, 0, stream>>>(psum, NBLK);
    k_scan3<<<NBLK, 256, 0, stream>>>(off, psum, cur);
    k_place<<<(NEV + 255) / 256, 256, 0, stream>>>(src, dst, tarr, last_update, cur, entries);
    tgn_gemm<<<NTILE, 512, 0, stream>>>(membf, rawbf, entries, time_w, time_b,
                                        Bp, b_ih, b_hh, cnt, off, out);
}